// Round 1
// baseline (7226.471 us; speedup 1.0000x reference)
//
#include <hip/hip_runtime.h>

#define B_  32
#define S_  512
#define E_  768
#define HH_ 384
#define G4  1536
#define NT  17

typedef __attribute__((ext_vector_type(8))) short short8;
typedef __attribute__((ext_vector_type(4))) float f32x4;

static __device__ __forceinline__ unsigned short f2bf(float x) {
  unsigned u = __float_as_uint(x);
  u = u + 0x7fffu + ((u >> 16) & 1u);
  return (unsigned short)(u >> 16);
}
static __device__ __forceinline__ float bf2f(unsigned short h) {
  return __uint_as_float(((unsigned)h) << 16);
}
static __device__ __forceinline__ float sigm(float x) {
  return 1.0f / (1.0f + __expf(-x));
}

__global__ __launch_bounds__(256) void cvt_bf16(const float* __restrict__ in,
                                                unsigned short* __restrict__ out, int n) {
  for (int i = blockIdx.x * blockDim.x + threadIdx.x; i < n; i += gridDim.x * blockDim.x)
    out[i] = f2bf(in[i]);
}

// ---------------- Input GEMM: G[d][s][b][1536] = emb[b][s][:] @ W_ih[d]^T + bias -----------
// C = A * B^T, A rows = emb rows (bf16), B rows = W_ih rows (bf16), K = 768.
// 128x128 tile, BK=32, 4 waves (2x2 quadrants of 64x64), st_16x32 LDS swizzle.
__global__ __launch_bounds__(256) void gemm_input(
    const unsigned short* __restrict__ embB,   // [32][512][768] bf16
    const unsigned short* __restrict__ WihB,   // [2][1536][768] bf16
    const float* __restrict__ bf, const float* __restrict__ bb,
    float* __restrict__ G)                     // [2][512*32][1536] fp32
{
  const int d  = blockIdx.z;
  const int n0 = blockIdx.x * 128;
  const int m0 = blockIdx.y * 128;
  const unsigned short* Wd = WihB + (size_t)d * G4 * E_;
  const float* bias = d ? bb : bf;

  __shared__ char As[8192];
  __shared__ char Bs[8192];

  const int tid = threadIdx.x;
  const int wave = tid >> 6, lane = tid & 63;
  const int mq = (wave >> 1) * 64, nq = (wave & 1) * 64;

  f32x4 acc[4][4] = {};

  for (int k0 = 0; k0 < E_; k0 += 32) {
    __syncthreads();
    // stage A and B: 8 chunks of 1KB each; this wave does chunks wave*2, wave*2+1
    #pragma unroll
    for (int i = 0; i < 2; ++i) {
      int chunk = wave * 2 + i;
      int p = chunk * 1024 + lane * 16;            // physical byte this lane fills
      int q = p ^ (((p >> 9) & 1) << 5);           // logical byte (st_16x32 involution)
      int row = q >> 6;                            // 0..127
      int ke  = (q & 63) >> 1;                     // bf16 element 0..31
      { // A
        int r = m0 + row; int ss = r >> 5; int bb_ = r & 31;
        const unsigned short* src = embB + ((size_t)bb_ * S_ + ss) * E_ + k0 + ke;
        __builtin_amdgcn_global_load_lds((const __attribute__((address_space(1))) unsigned int*)src,
            (__attribute__((address_space(3))) unsigned int*)(As + chunk * 1024), 16, 0, 0);
      }
      { // B
        const unsigned short* src = Wd + (size_t)(n0 + row) * E_ + k0 + ke;
        __builtin_amdgcn_global_load_lds((const __attribute__((address_space(1))) unsigned int*)src,
            (__attribute__((address_space(3))) unsigned int*)(Bs + chunk * 1024), 16, 0, 0);
      }
    }
    asm volatile("s_waitcnt vmcnt(0)" ::: "memory");
    __syncthreads();

    short8 af[4], bfm[4];
    int kbyte = ((lane >> 4) * 8) * 2;
    #pragma unroll
    for (int mt = 0; mt < 4; ++mt) {
      int p = (mq + mt * 16 + (lane & 15)) * 64 + kbyte;
      int q = p ^ (((p >> 9) & 1) << 5);
      af[mt] = *(const short8*)(As + q);
    }
    #pragma unroll
    for (int nt = 0; nt < 4; ++nt) {
      int p = (nq + nt * 16 + (lane & 15)) * 64 + kbyte;
      int q = p ^ (((p >> 9) & 1) << 5);
      bfm[nt] = *(const short8*)(Bs + q);
    }
    #pragma unroll
    for (int mt = 0; mt < 4; ++mt)
      #pragma unroll
      for (int nt = 0; nt < 4; ++nt)
        acc[mt][nt] = __builtin_amdgcn_mfma_f32_16x16x32_bf16(af[mt], bfm[nt], acc[mt][nt], 0, 0, 0);
  }

  // epilogue: C row = batch-major row (s*32+b), col = gate row; C layout col=lane&15,row=(lane>>4)*4+r
  #pragma unroll
  for (int nt = 0; nt < 4; ++nt) {
    int col = n0 + nq + nt * 16 + (lane & 15);
    float bv = bias[col];
    #pragma unroll
    for (int mt = 0; mt < 4; ++mt) {
      int grow0 = m0 + mq + mt * 16 + (lane >> 4) * 4;
      #pragma unroll
      for (int r = 0; r < 4; ++r)
        G[((size_t)d * (S_ * B_) + grow0 + r) * G4 + col] = acc[mt][nt][r] + bv;
    }
  }
}

// ---------------- Persistent recurrent LSTM ------------------------------------------------
// 48 WGs: WG w -> dir d = w&1, wi = w>>1 (0..23) owns h-indices [wi*16, wi*16+16).
// Wave q holds W_hh B-fragments for gate q (48 VGPRs, loaded once).
// Per step: A-frags from previous h (global, bf16), acc init from G, 24 MFMAs,
// gate exchange via LDS, h/c update, h broadcast via global + device barrier.
__global__ __launch_bounds__(256) void lstm_rec(
    const unsigned short* __restrict__ WhhB,   // [2][1536][384] bf16
    const unsigned short* __restrict__ hinit,  // [2][32][384] bf16
    const float* __restrict__ c0,              // [2][32][384] fp32
    const float* __restrict__ G,               // [2][512*32][1536] fp32
    unsigned short* __restrict__ hall,         // [2][512][32][384] bf16
    unsigned* __restrict__ bar)                // [4]: cntF genF cntB genB
{
  const int w   = blockIdx.x;
  const int d   = w & 1;
  const int wi  = w >> 1;
  const int j0  = wi * 16;
  const int tid = threadIdx.x, wave = tid >> 6, lane = tid & 63;

  __shared__ float g_lds[4][32][16];
  __shared__ float c_lds[32][16];

  // B-fragments: W_hh[d] row = wave*384 + j0 + (lane&15), k = ks*32 + (lane>>4)*8 + j
  short8 Bf[12];
  {
    const unsigned short* Wd = WhhB + (size_t)d * G4 * HH_;
    const unsigned short* rp = Wd + (size_t)(wave * HH_ + j0 + (lane & 15)) * HH_ + (lane >> 4) * 8;
    #pragma unroll
    for (int ks = 0; ks < 12; ++ks)
      Bf[ks] = *(const short8*)(rp + ks * 32);
  }
  // c init
  for (int p = tid; p < 512; p += 256) {
    int b_ = p >> 4, jj = p & 15;
    c_lds[b_][jj] = c0[((size_t)d * B_ + b_) * HH_ + j0 + jj];
  }
  __syncthreads();

  unsigned* cnt = bar + d * 2;
  unsigned* gen = bar + d * 2 + 1;

  for (int t = 0; t < S_; ++t) {
    const int s = d ? (S_ - 1 - t) : t;
    const unsigned short* hsrc = (t == 0)
        ? (hinit + (size_t)d * B_ * HH_)
        : (hall + ((size_t)d * S_ + (d ? s + 1 : s - 1)) * B_ * HH_);

    // A-fragments (2 row-tiles x 12 k-steps) direct from global
    short8 Af[2][12];
    const int kb = (lane >> 4) * 8;
    #pragma unroll
    for (int mt = 0; mt < 2; ++mt) {
      const unsigned short* hp = hsrc + (size_t)(mt * 16 + (lane & 15)) * HH_ + kb;
      #pragma unroll
      for (int ks = 0; ks < 12; ++ks)
        Af[mt][ks] = *(const short8*)(hp + ks * 32);
    }

    // acc init from G (gate pre-activations from input projection, bias included)
    const float* Gs = G + ((size_t)d * S_ + s) * B_ * G4 + wave * HH_ + j0 + (lane & 15);
    f32x4 acc[2];
    #pragma unroll
    for (int mt = 0; mt < 2; ++mt)
      #pragma unroll
      for (int r = 0; r < 4; ++r)
        acc[mt][r] = Gs[(size_t)((lane >> 4) * 4 + r + mt * 16) * G4];

    #pragma unroll
    for (int mt = 0; mt < 2; ++mt)
      #pragma unroll
      for (int ks = 0; ks < 12; ++ks)
        acc[mt] = __builtin_amdgcn_mfma_f32_16x16x32_bf16(Af[mt][ks], Bf[ks], acc[mt], 0, 0, 0);

    // exchange gates through LDS
    #pragma unroll
    for (int mt = 0; mt < 2; ++mt)
      #pragma unroll
      for (int r = 0; r < 4; ++r)
        g_lds[wave][(lane >> 4) * 4 + r + mt * 16][lane & 15] = acc[mt][r];
    __syncthreads();

    // h, c update for our 16 h-indices x 32 batches
    for (int p = tid; p < 512; p += 256) {
      int b_ = p >> 4, jj = p & 15;
      float iv = g_lds[0][b_][jj];
      float fv = g_lds[1][b_][jj];
      float gv = g_lds[2][b_][jj];
      float ov = g_lds[3][b_][jj];
      float c = sigm(fv) * c_lds[b_][jj] + sigm(iv) * tanhf(gv);
      float h = sigm(ov) * tanhf(c);
      c_lds[b_][jj] = c;
      hall[(((size_t)d * S_ + s) * B_ + b_) * HH_ + j0 + jj] = f2bf(h);
    }
    __syncthreads();

    // device-scope barrier (per direction) with cross-XCD visibility fences
    __threadfence();
    __syncthreads();
    if (tid == 0) {
      unsigned a = __hip_atomic_fetch_add(cnt, 1u, __ATOMIC_ACQ_REL, __HIP_MEMORY_SCOPE_AGENT);
      if (a == 23u) {
        __hip_atomic_store(cnt, 0u, __ATOMIC_RELAXED, __HIP_MEMORY_SCOPE_AGENT);
        __hip_atomic_store(gen, (unsigned)(t + 1), __ATOMIC_RELEASE, __HIP_MEMORY_SCOPE_AGENT);
      } else {
        while (__hip_atomic_load(gen, __ATOMIC_ACQUIRE, __HIP_MEMORY_SCOPE_AGENT) < (unsigned)(t + 1)) {}
      }
    }
    __syncthreads();
    __threadfence();
  }
}

// ---------------- Logits: [b][s][17] = concat(hf,hb) @ W_tag^T + b_tag ---------------------
__global__ __launch_bounds__(544) void logits_k(
    const unsigned short* __restrict__ hall,
    const float* __restrict__ Wtag, const float* __restrict__ btag,
    float* __restrict__ logits)
{
  int s = blockIdx.x;
  int t = threadIdx.x;
  int b_ = t / NT, n = t % NT;
  if (b_ >= B_) return;
  const unsigned short* hf = hall + ((size_t)0 * S_ + s) * B_ * HH_ + (size_t)b_ * HH_;
  const unsigned short* hb = hall + ((size_t)1 * S_ + s) * B_ * HH_ + (size_t)b_ * HH_;
  const float* wv = Wtag + (size_t)n * (2 * HH_);
  float acc = btag[n];
  for (int k = 0; k < HH_; ++k) acc += bf2f(hf[k]) * wv[k];
  for (int k = 0; k < HH_; ++k) acc += bf2f(hb[k]) * wv[HH_ + k];
  logits[((size_t)b_ * S_ + s) * NT + n] = acc;
}

// ---------------- Viterbi (faithful: lse alpha + argmax backpointers) ----------------------
__global__ __launch_bounds__(64) void viterbi(
    const float* __restrict__ logits,   // [32][512][17]
    const int* __restrict__ mask,       // [32][512]
    const float* __restrict__ trans,    // [17][17]
    float* __restrict__ out)            // [32] scores then [32][512] paths (as float)
{
  const int b = blockIdx.x;
  const int lane = threadIdx.x;
  __shared__ float tr[NT * NT];
  __shared__ float alpha[NT];
  __shared__ signed char bp[S_][NT];
  __shared__ int len_s;

  int cnt = 0;
  for (int t = lane; t < S_; t += 64) cnt += mask[(size_t)b * S_ + t];
  #pragma unroll
  for (int o = 32; o > 0; o >>= 1) cnt += __shfl_down(cnt, o);
  if (lane == 0) len_s = cnt;
  for (int i = lane; i < NT * NT; i += 64) tr[i] = trans[i];
  if (lane < NT) alpha[lane] = (lane == 15) ? 0.0f : -1000.0f;
  __syncthreads();
  const int len = len_s;
  const float* lg = logits + (size_t)b * S_ * NT;

  for (int t = 0; t < S_; ++t) {
    float na = 0.f; signed char am = 0;
    if (lane < NT) {
      float v[NT];
      float best = -3.4e38f; int arg = 0;
      #pragma unroll
      for (int p = 0; p < NT; ++p) {
        float x = alpha[p] + tr[p * NT + lane];
        v[p] = x;
        if (x > best) { best = x; arg = p; }   // strict > keeps first max (jnp.argmax)
      }
      float ssum = 0.f;
      #pragma unroll
      for (int p = 0; p < NT; ++p) ssum += __expf(v[p] - best);
      na = lg[t * NT + lane] + best + __logf(ssum);
      am = (signed char)arg;
    }
    __syncthreads();
    if (lane < NT) {
      if (t < len) alpha[lane] = na;
      bp[t][lane] = am;
    }
    __syncthreads();
  }

  if (lane == 0) {
    float fin[NT];
    float best = -3.4e38f; int arg = 0;
    #pragma unroll
    for (int n = 0; n < NT; ++n) {
      fin[n] = alpha[n] + tr[n * NT + 16];
      if (fin[n] > best) { best = fin[n]; arg = n; }
    }
    float ss = 0.f;
    #pragma unroll
    for (int n = 0; n < NT; ++n) ss += __expf(fin[n] - best);
    out[b] = best + __logf(ss);

    int tag = arg;
    float* po = out + B_ + (size_t)b * S_;
    for (int t = S_ - 1; t >= 0; --t) {
      int nt;
      if (t == len - 1) nt = arg;
      else if (t < len - 1) nt = bp[t + 1][tag];
      else nt = tag;
      tag = nt;
      po[t] = (t < len) ? (float)nt : -1.0f;
    }
  }
}

extern "C" void kernel_launch(void* const* d_in, const int* in_sizes, int n_in,
                              void* d_out, int out_size, void* d_ws, size_t ws_size,
                              hipStream_t stream) {
  const float* emb   = (const float*)d_in[0];
  const int*   maskp = (const int*)d_in[1];
  const float* h0    = (const float*)d_in[2];
  const float* c0    = (const float*)d_in[3];
  const float* Wihf  = (const float*)d_in[4];
  const float* Whhf  = (const float*)d_in[5];
  const float* bfp   = (const float*)d_in[6];
  const float* Wihb  = (const float*)d_in[7];
  const float* Whhb  = (const float*)d_in[8];
  const float* bbp   = (const float*)d_in[9];
  const float* Wtag  = (const float*)d_in[10];
  const float* btag  = (const float*)d_in[11];
  const float* trans = (const float*)d_in[12];
  float* out = (float*)d_out;

  char* ws = (char*)d_ws;
  const size_t szG    = (size_t)2 * S_ * B_ * G4 * 4;      // 201326592
  const size_t szEmb  = (size_t)B_ * S_ * E_ * 2;          // 25165824
  const size_t szWih  = (size_t)2 * G4 * E_ * 2;           // 4718592
  const size_t szWhh  = (size_t)2 * G4 * HH_ * 2;          // 2359296
  const size_t szHin  = (size_t)2 * B_ * HH_ * 2;          // 49152
  const size_t szHall = (size_t)2 * S_ * B_ * HH_ * 2;     // 25165824
  const size_t szLog  = (size_t)B_ * S_ * NT * 4;          // 1114112

  size_t off = 0;
  float*          G      = (float*)(ws + off);          off += szG;
  unsigned short* embB   = (unsigned short*)(ws + off); off += szEmb;
  unsigned short* WihB   = (unsigned short*)(ws + off); off += szWih;
  unsigned short* WhhB   = (unsigned short*)(ws + off); off += szWhh;
  unsigned short* hinitB = (unsigned short*)(ws + off); off += szHin;
  unsigned short* hallB  = (unsigned short*)(ws + off); off += szHall;
  float*          logits = (float*)(ws + off);          off += szLog;
  unsigned*       bar    = (unsigned*)(ws + off);       off += 64;
  if (ws_size < off) return;  // workspace too small — bail (will show as absmax fail)

  hipMemsetAsync(bar, 0, 64, stream);

  cvt_bf16<<<2048, 256, 0, stream>>>(emb,  embB, B_ * S_ * E_);
  cvt_bf16<<<256, 256, 0, stream>>>(Wihf, WihB, G4 * E_);
  cvt_bf16<<<256, 256, 0, stream>>>(Wihb, WihB + (size_t)G4 * E_, G4 * E_);
  cvt_bf16<<<128, 256, 0, stream>>>(Whhf, WhhB, G4 * HH_);
  cvt_bf16<<<128, 256, 0, stream>>>(Whhb, WhhB + (size_t)G4 * HH_, G4 * HH_);
  cvt_bf16<<<48, 256, 0, stream>>>(h0, hinitB, 2 * B_ * HH_);

  gemm_input<<<dim3(G4 / 128, (S_ * B_) / 128, 2), 256, 0, stream>>>(embB, WihB, bfp, bbp, G);
  lstm_rec<<<48, 256, 0, stream>>>(WhhB, hinitB, c0, G, hallB, bar);
  logits_k<<<S_, 544, 0, stream>>>(hallB, Wtag, btag, logits);
  viterbi<<<B_, 64, 0, stream>>>(logits, maskp, trans, out);

  (void)in_sizes; (void)n_in; (void)out_size; (void)ws_size;
}

// Round 2
// 7176.805 us; speedup vs baseline: 1.0069x; 1.0069x over previous
//
#include <hip/hip_runtime.h>

#define B_  32
#define S_  512
#define E_  768
#define HH_ 384
#define G4  1536
#define NT  17

typedef __attribute__((ext_vector_type(8))) short short8;
typedef __attribute__((ext_vector_type(4))) float f32x4;

static __device__ __forceinline__ unsigned short f2bf(float x) {
  unsigned u = __float_as_uint(x);
  u = u + 0x7fffu + ((u >> 16) & 1u);
  return (unsigned short)(u >> 16);
}
static __device__ __forceinline__ float bf2f(unsigned short h) {
  return __uint_as_float(((unsigned)h) << 16);
}
static __device__ __forceinline__ float sigm(float x) {
  return 1.0f / (1.0f + __expf(-x));
}
static __device__ __forceinline__ float tanh_fast(float x) {
  float t = __expf(-2.0f * fabsf(x));
  float r = (1.0f - t) / (1.0f + t);   // stable: t<=1, no overflow
  return copysignf(r, x);
}

__global__ __launch_bounds__(256) void cvt_bf16(const float* __restrict__ in,
                                                unsigned short* __restrict__ out, int n) {
  for (int i = blockIdx.x * blockDim.x + threadIdx.x; i < n; i += gridDim.x * blockDim.x)
    out[i] = f2bf(in[i]);
}

// ---------------- Input GEMM: G[d][s*32+b][1536] = emb[b][s][:] @ W_ih[d]^T + bias ---------
__global__ __launch_bounds__(256) void gemm_input(
    const unsigned short* __restrict__ embB,   // [32][512][768] bf16
    const unsigned short* __restrict__ WihB,   // [2][1536][768] bf16
    const float* __restrict__ bf, const float* __restrict__ bb,
    float* __restrict__ G)                     // [2][512*32][1536] fp32
{
  const int d  = blockIdx.z;
  const int n0 = blockIdx.x * 128;
  const int m0 = blockIdx.y * 128;
  const unsigned short* Wd = WihB + (size_t)d * G4 * E_;
  const float* bias = d ? bb : bf;

  __shared__ char As[8192];
  __shared__ char Bs[8192];

  const int tid = threadIdx.x;
  const int wave = tid >> 6, lane = tid & 63;
  const int mq = (wave >> 1) * 64, nq = (wave & 1) * 64;

  f32x4 acc[4][4] = {};

  for (int k0 = 0; k0 < E_; k0 += 32) {
    __syncthreads();
    #pragma unroll
    for (int i = 0; i < 2; ++i) {
      int chunk = wave * 2 + i;
      int p = chunk * 1024 + lane * 16;            // physical byte this lane fills
      int q = p ^ (((p >> 9) & 1) << 5);           // logical byte (st_16x32 involution)
      int row = q >> 6;                            // 0..127
      int ke  = (q & 63) >> 1;                     // bf16 element 0..31
      { // A
        int r = m0 + row; int ss = r >> 5; int bb_ = r & 31;
        const unsigned short* src = embB + ((size_t)bb_ * S_ + ss) * E_ + k0 + ke;
        __builtin_amdgcn_global_load_lds((const __attribute__((address_space(1))) unsigned int*)src,
            (__attribute__((address_space(3))) unsigned int*)(As + chunk * 1024), 16, 0, 0);
      }
      { // B
        const unsigned short* src = Wd + (size_t)(n0 + row) * E_ + k0 + ke;
        __builtin_amdgcn_global_load_lds((const __attribute__((address_space(1))) unsigned int*)src,
            (__attribute__((address_space(3))) unsigned int*)(Bs + chunk * 1024), 16, 0, 0);
      }
    }
    asm volatile("s_waitcnt vmcnt(0)" ::: "memory");
    __syncthreads();

    short8 af[4], bfm[4];
    int kbyte = ((lane >> 4) * 8) * 2;
    #pragma unroll
    for (int mt = 0; mt < 4; ++mt) {
      int p = (mq + mt * 16 + (lane & 15)) * 64 + kbyte;
      int q = p ^ (((p >> 9) & 1) << 5);
      af[mt] = *(const short8*)(As + q);
    }
    #pragma unroll
    for (int nt = 0; nt < 4; ++nt) {
      int p = (nq + nt * 16 + (lane & 15)) * 64 + kbyte;
      int q = p ^ (((p >> 9) & 1) << 5);
      bfm[nt] = *(const short8*)(Bs + q);
    }
    #pragma unroll
    for (int mt = 0; mt < 4; ++mt)
      #pragma unroll
      for (int nt = 0; nt < 4; ++nt)
        acc[mt][nt] = __builtin_amdgcn_mfma_f32_16x16x32_bf16(af[mt], bfm[nt], acc[mt][nt], 0, 0, 0);
  }

  #pragma unroll
  for (int nt = 0; nt < 4; ++nt) {
    int col = n0 + nq + nt * 16 + (lane & 15);
    float bv = bias[col];
    #pragma unroll
    for (int mt = 0; mt < 4; ++mt) {
      int grow0 = m0 + mq + mt * 16 + (lane >> 4) * 4;
      #pragma unroll
      for (int r = 0; r < 4; ++r)
        G[((size_t)d * (S_ * B_) + grow0 + r) * G4 + col] = acc[mt][nt][r] + bv;
    }
  }
}

// ---------------- Persistent recurrent LSTM ------------------------------------------------
// 8 WGs x 512 threads: WG w -> dir d = w>>2, wi = w&3 owns h-indices [wi*96, wi*96+96).
// Wave q: gate g = q>>1, h-sub-block (q&1)*48 (3 nt tiles of 16).
// W_hh B-frags in registers (144 VGPR/lane). Per step: A-frags from prev h (global bf16),
// acc init from register-prefetched G, 72 MFMAs/wave, LDS gate exchange, h/c update,
// h broadcast via global + 4-party per-direction device barrier. Next-step G prefetched
// into registers BEFORE the barrier spin (latency hidden under barrier wait).
__global__ __launch_bounds__(512) void lstm_rec(
    const unsigned short* __restrict__ WhhB,   // [2][1536][384] bf16
    const unsigned short* __restrict__ hinit,  // [2][32][384] bf16
    const float* __restrict__ c0,              // [2][32][384] fp32
    const float* __restrict__ G,               // [2][512*32][1536] fp32
    unsigned short* __restrict__ hall,         // [2][512][32][384] bf16
    unsigned* __restrict__ bar)                // per-dir cnt/gen, 256B apart
{
  const int w   = blockIdx.x;        // 0..7
  const int d   = w >> 2;
  const int wi  = w & 3;
  const int j0  = wi * 96;
  const int tid = threadIdx.x, wave = tid >> 6, lane = tid & 63;
  const int g   = wave >> 1;
  const int hq  = (wave & 1) * 48;
  const int l15 = lane & 15, l4 = lane >> 4;

  __shared__ float g_lds[4][32][97];   // +1 pad breaks 96-stride bank aliasing
  __shared__ float c_lds[32][97];

  const int growbase = g * 384 + j0 + hq;   // + nt*16 + l15 = W_hh gate-row

  // B-fragments: row = gate-row, k = ks*32 + l4*8 + e
  short8 Bf[3][12];
  {
    const unsigned short* Wd = WhhB + (size_t)d * G4 * HH_;
    #pragma unroll
    for (int nt = 0; nt < 3; ++nt) {
      const unsigned short* rp = Wd + (size_t)(growbase + nt * 16 + l15) * HH_ + l4 * 8;
      #pragma unroll
      for (int ks = 0; ks < 12; ++ks)
        Bf[nt][ks] = *(const short8*)(rp + ks * 32);
    }
  }
  for (int p = tid; p < 32 * 96; p += 512) {
    int b_ = p / 96, jj = p - b_ * 96;
    c_lds[b_][jj] = c0[((size_t)d * B_ + b_) * HH_ + j0 + jj];
  }

  unsigned* cnt = bar + d * 64;        // 256B per direction: no false sharing
  unsigned* gen = bar + d * 64 + 32;   // gen on its own 128B line

  // G prefetch for t=0
  float gp[2][3][4];
  {
    int s0 = d ? (S_ - 1) : 0;
    const float* Gs = G + (size_t)(d * S_ + s0) * B_ * G4;
    #pragma unroll
    for (int mt = 0; mt < 2; ++mt)
      #pragma unroll
      for (int nt = 0; nt < 3; ++nt)
        #pragma unroll
        for (int r = 0; r < 4; ++r)
          gp[mt][nt][r] = Gs[(size_t)(mt * 16 + l4 * 4 + r) * G4 + growbase + nt * 16 + l15];
  }
  __syncthreads();

  for (int t = 0; t < S_; ++t) {
    const int s = d ? (S_ - 1 - t) : t;
    const unsigned short* hsrc = (t == 0)
        ? (hinit + (size_t)d * B_ * HH_)
        : (hall + ((size_t)d * S_ + (d ? s + 1 : s - 1)) * B_ * HH_);

    f32x4 acc[2][3];
    #pragma unroll
    for (int mt = 0; mt < 2; ++mt)
      #pragma unroll
      for (int nt = 0; nt < 3; ++nt)
        #pragma unroll
        for (int r = 0; r < 4; ++r)
          acc[mt][nt][r] = gp[mt][nt][r];

    const int kb = l4 * 8;
    #pragma unroll
    for (int ks = 0; ks < 12; ++ks) {
      short8 a0 = *(const short8*)(hsrc + (size_t)l15 * HH_ + ks * 32 + kb);
      short8 a1 = *(const short8*)(hsrc + (size_t)(16 + l15) * HH_ + ks * 32 + kb);
      #pragma unroll
      for (int nt = 0; nt < 3; ++nt) {
        acc[0][nt] = __builtin_amdgcn_mfma_f32_16x16x32_bf16(a0, Bf[nt][ks], acc[0][nt], 0, 0, 0);
        acc[1][nt] = __builtin_amdgcn_mfma_f32_16x16x32_bf16(a1, Bf[nt][ks], acc[1][nt], 0, 0, 0);
      }
    }

    // gate exchange through LDS
    #pragma unroll
    for (int mt = 0; mt < 2; ++mt)
      #pragma unroll
      for (int nt = 0; nt < 3; ++nt)
        #pragma unroll
        for (int r = 0; r < 4; ++r)
          g_lds[g][mt * 16 + l4 * 4 + r][hq + nt * 16 + l15] = acc[mt][nt][r];
    __syncthreads();

    // h/c update for our 96 h-indices x 32 batches
    for (int p = tid; p < 32 * 96; p += 512) {
      int b_ = p / 96, jj = p - b_ * 96;
      float iv = g_lds[0][b_][jj];
      float fv = g_lds[1][b_][jj];
      float gv = g_lds[2][b_][jj];
      float ov = g_lds[3][b_][jj];
      float c = sigm(fv) * c_lds[b_][jj] + sigm(iv) * tanh_fast(gv);
      float h = sigm(ov) * tanh_fast(c);
      c_lds[b_][jj] = c;
      hall[(((size_t)d * S_ + s) * B_ + b_) * HH_ + j0 + jj] = f2bf(h);
    }
    __syncthreads();
    __threadfence();      // flush my h stores device-wide
    __syncthreads();      // whole WG fenced

    // prefetch next-step G now; its HBM latency hides under the barrier spin
    if (t + 1 < S_) {
      int s2 = d ? (S_ - 2 - t) : (t + 1);
      const float* Gs = G + (size_t)(d * S_ + s2) * B_ * G4;
      #pragma unroll
      for (int mt = 0; mt < 2; ++mt)
        #pragma unroll
        for (int nt = 0; nt < 3; ++nt)
          #pragma unroll
          for (int r = 0; r < 4; ++r)
            gp[mt][nt][r] = Gs[(size_t)(mt * 16 + l4 * 4 + r) * G4 + growbase + nt * 16 + l15];
    }

    // 4-party per-direction device barrier
    if (tid == 0) {
      unsigned a = __hip_atomic_fetch_add(cnt, 1u, __ATOMIC_ACQ_REL, __HIP_MEMORY_SCOPE_AGENT);
      if (a == 3u) {
        __hip_atomic_store(cnt, 0u, __ATOMIC_RELAXED, __HIP_MEMORY_SCOPE_AGENT);
        __hip_atomic_store(gen, (unsigned)(t + 1), __ATOMIC_RELEASE, __HIP_MEMORY_SCOPE_AGENT);
      } else {
        while (__hip_atomic_load(gen, __ATOMIC_ACQUIRE, __HIP_MEMORY_SCOPE_AGENT) < (unsigned)(t + 1)) {}
      }
    }
    __syncthreads();
    __threadfence();      // acquire side: invalidate stale h before next read
  }
}

// ---------------- Logits: [b][s][17] = concat(hf,hb) @ W_tag^T + b_tag ---------------------
__global__ __launch_bounds__(256) void logits_k(
    const unsigned short* __restrict__ hall,
    const float* __restrict__ Wtag, const float* __restrict__ btag,
    float* __restrict__ logits)
{
  int gid = blockIdx.x * blockDim.x + threadIdx.x;
  if (gid >= B_ * S_ * NT) return;
  int n = gid % NT, bs = gid / NT;
  int b_ = bs / S_, s = bs - b_ * S_;
  const unsigned short* hf = hall + (((size_t)0 * S_ + s) * B_ + b_) * HH_;
  const unsigned short* hb = hall + (((size_t)1 * S_ + s) * B_ + b_) * HH_;
  const float* w0 = Wtag + (size_t)n * (2 * HH_);
  float acc = btag[n];
  for (int k = 0; k < HH_; k += 8) {
    short8 hv = *(const short8*)(hf + k);
    #pragma unroll
    for (int j = 0; j < 8; ++j) acc += bf2f((unsigned short)hv[j]) * w0[k + j];
  }
  for (int k = 0; k < HH_; k += 8) {
    short8 hv = *(const short8*)(hb + k);
    #pragma unroll
    for (int j = 0; j < 8; ++j) acc += bf2f((unsigned short)hv[j]) * w0[HH_ + k + j];
  }
  logits[((size_t)b_ * S_ + s) * NT + n] = acc;
}

// ---------------- Viterbi (faithful: lse alpha + argmax backpointers) ----------------------
__global__ __launch_bounds__(64) void viterbi(
    const float* __restrict__ logits,   // [32][512][17]
    const int* __restrict__ mask,       // [32][512]
    const float* __restrict__ trans,    // [17][17]
    float* __restrict__ out)            // [32] scores then [32][512] paths (as float)
{
  const int b = blockIdx.x;
  const int lane = threadIdx.x;
  __shared__ float tr[NT * NT];
  __shared__ float alpha[NT];
  __shared__ signed char bp[S_][NT];
  __shared__ int len_s;

  int cnt = 0;
  for (int t = lane; t < S_; t += 64) cnt += mask[(size_t)b * S_ + t];
  #pragma unroll
  for (int o = 32; o > 0; o >>= 1) cnt += __shfl_down(cnt, o);
  if (lane == 0) len_s = cnt;
  for (int i = lane; i < NT * NT; i += 64) tr[i] = trans[i];
  if (lane < NT) alpha[lane] = (lane == 15) ? 0.0f : -1000.0f;
  __syncthreads();
  const int len = len_s;
  const float* lg = logits + (size_t)b * S_ * NT;

  for (int t = 0; t < S_; ++t) {
    float na = 0.f; signed char am = 0;
    if (lane < NT) {
      float v[NT];
      float best = -3.4e38f; int arg = 0;
      #pragma unroll
      for (int p = 0; p < NT; ++p) {
        float x = alpha[p] + tr[p * NT + lane];
        v[p] = x;
        if (x > best) { best = x; arg = p; }   // strict > keeps first max (jnp.argmax)
      }
      float ssum = 0.f;
      #pragma unroll
      for (int p = 0; p < NT; ++p) ssum += __expf(v[p] - best);
      na = lg[t * NT + lane] + best + __logf(ssum);
      am = (signed char)arg;
    }
    __syncthreads();
    if (lane < NT) {
      if (t < len) alpha[lane] = na;
      bp[t][lane] = am;
    }
    __syncthreads();
  }

  if (lane == 0) {
    float fin[NT];
    float best = -3.4e38f; int arg = 0;
    #pragma unroll
    for (int n = 0; n < NT; ++n) {
      fin[n] = alpha[n] + tr[n * NT + 16];
      if (fin[n] > best) { best = fin[n]; arg = n; }
    }
    float ss = 0.f;
    #pragma unroll
    for (int n = 0; n < NT; ++n) ss += __expf(fin[n] - best);
    out[b] = best + __logf(ss);

    int tag = arg;
    float* po = out + B_ + (size_t)b * S_;
    for (int t = S_ - 1; t >= 0; --t) {
      int nt;
      if (t == len - 1) nt = arg;
      else if (t < len - 1) nt = bp[t + 1][tag];
      else nt = tag;
      tag = nt;
      po[t] = (t < len) ? (float)nt : -1.0f;
    }
  }
}

extern "C" void kernel_launch(void* const* d_in, const int* in_sizes, int n_in,
                              void* d_out, int out_size, void* d_ws, size_t ws_size,
                              hipStream_t stream) {
  const float* emb   = (const float*)d_in[0];
  const int*   maskp = (const int*)d_in[1];
  const float* h0    = (const float*)d_in[2];
  const float* c0    = (const float*)d_in[3];
  const float* Wihf  = (const float*)d_in[4];
  const float* Whhf  = (const float*)d_in[5];
  const float* bfp   = (const float*)d_in[6];
  const float* Wihb  = (const float*)d_in[7];
  const float* Whhb  = (const float*)d_in[8];
  const float* bbp   = (const float*)d_in[9];
  const float* Wtag  = (const float*)d_in[10];
  const float* btag  = (const float*)d_in[11];
  const float* trans = (const float*)d_in[12];
  float* out = (float*)d_out;

  char* ws = (char*)d_ws;
  const size_t szG    = (size_t)2 * S_ * B_ * G4 * 4;
  const size_t szEmb  = (size_t)B_ * S_ * E_ * 2;
  const size_t szWih  = (size_t)2 * G4 * E_ * 2;
  const size_t szWhh  = (size_t)2 * G4 * HH_ * 2;
  const size_t szHin  = (size_t)2 * B_ * HH_ * 2;
  const size_t szHall = (size_t)2 * S_ * B_ * HH_ * 2;
  const size_t szLog  = (size_t)B_ * S_ * NT * 4;

  size_t off = 0;
  float*          G      = (float*)(ws + off);          off += szG;
  unsigned short* embB   = (unsigned short*)(ws + off); off += szEmb;
  unsigned short* WihB   = (unsigned short*)(ws + off); off += szWih;
  unsigned short* WhhB   = (unsigned short*)(ws + off); off += szWhh;
  unsigned short* hinitB = (unsigned short*)(ws + off); off += szHin;
  unsigned short* hallB  = (unsigned short*)(ws + off); off += szHall;
  float*          logits = (float*)(ws + off);          off += szLog;
  unsigned*       bar    = (unsigned*)(ws + off);       off += 512;
  if (ws_size < off) return;

  hipMemsetAsync(bar, 0, 512, stream);

  cvt_bf16<<<2048, 256, 0, stream>>>(emb,  embB, B_ * S_ * E_);
  cvt_bf16<<<256, 256, 0, stream>>>(Wihf, WihB, G4 * E_);
  cvt_bf16<<<256, 256, 0, stream>>>(Wihb, WihB + (size_t)G4 * E_, G4 * E_);
  cvt_bf16<<<128, 256, 0, stream>>>(Whhf, WhhB, G4 * HH_);
  cvt_bf16<<<128, 256, 0, stream>>>(Whhb, WhhB + (size_t)G4 * HH_, G4 * HH_);
  cvt_bf16<<<48, 256, 0, stream>>>(h0, hinitB, 2 * B_ * HH_);

  gemm_input<<<dim3(G4 / 128, (S_ * B_) / 128, 2), 256, 0, stream>>>(embB, WihB, bfp, bbp, G);
  lstm_rec<<<8, 512, 0, stream>>>(WhhB, hinitB, c0, G, hallB, bar);
  logits_k<<<(B_ * S_ * NT + 255) / 256, 256, 0, stream>>>(hallB, Wtag, btag, logits);
  viterbi<<<B_, 64, 0, stream>>>(logits, maskp, trans, out);

  (void)in_sizes; (void)n_in; (void)out_size; (void)ws_size;
}

// Round 3
// 5630.314 us; speedup vs baseline: 1.2835x; 1.2747x over previous
//
#include <hip/hip_runtime.h>

#define B_  32
#define S_  512
#define E_  768
#define HH_ 384
#define G4  1536
#define NT  17

typedef __attribute__((ext_vector_type(8))) short short8;
typedef __attribute__((ext_vector_type(4))) float f32x4;
typedef __attribute__((ext_vector_type(4))) unsigned uint4v;

static __device__ __forceinline__ unsigned short f2bf(float x) {
  unsigned u = __float_as_uint(x);
  u = u + 0x7fffu + ((u >> 16) & 1u);
  return (unsigned short)(u >> 16);
}
static __device__ __forceinline__ float bf2f(unsigned short h) {
  return __uint_as_float(((unsigned)h) << 16);
}
static __device__ __forceinline__ float sigm(float x) {
  return 1.0f / (1.0f + __expf(-x));
}
static __device__ __forceinline__ float tanh_fast(float x) {
  float t = __expf(-2.0f * fabsf(x));
  float r = (1.0f - t) / (1.0f + t);   // stable: t<=1, no overflow
  return copysignf(r, x);
}
// write-through store to device coherence point (no dirty L2 => no fence/flush needed)
static __device__ __forceinline__ void store_b128_wt(void* p, uint4v v) {
  asm volatile("global_store_dwordx4 %0, %1, off sc0 sc1" :: "v"(p), "v"(v) : "memory");
}

__global__ __launch_bounds__(256) void cvt_bf16(const float* __restrict__ in,
                                                unsigned short* __restrict__ out, int n) {
  for (int i = blockIdx.x * blockDim.x + threadIdx.x; i < n; i += gridDim.x * blockDim.x)
    out[i] = f2bf(in[i]);
}

// ---------------- Input GEMM: G[d][s*32+b][1536] = emb[b][s][:] @ W_ih[d]^T + bias ---------
__global__ __launch_bounds__(256) void gemm_input(
    const unsigned short* __restrict__ embB,   // [32][512][768] bf16
    const unsigned short* __restrict__ WihB,   // [2][1536][768] bf16
    const float* __restrict__ bf, const float* __restrict__ bb,
    float* __restrict__ G)                     // [2][512*32][1536] fp32
{
  const int d  = blockIdx.z;
  const int n0 = blockIdx.x * 128;
  const int m0 = blockIdx.y * 128;
  const unsigned short* Wd = WihB + (size_t)d * G4 * E_;
  const float* bias = d ? bb : bf;

  __shared__ char As[8192];
  __shared__ char Bs[8192];

  const int tid = threadIdx.x;
  const int wave = tid >> 6, lane = tid & 63;
  const int mq = (wave >> 1) * 64, nq = (wave & 1) * 64;

  f32x4 acc[4][4] = {};

  for (int k0 = 0; k0 < E_; k0 += 32) {
    __syncthreads();
    #pragma unroll
    for (int i = 0; i < 2; ++i) {
      int chunk = wave * 2 + i;
      int p = chunk * 1024 + lane * 16;            // physical byte this lane fills
      int q = p ^ (((p >> 9) & 1) << 5);           // logical byte (st_16x32 involution)
      int row = q >> 6;                            // 0..127
      int ke  = (q & 63) >> 1;                     // bf16 element 0..31
      { // A
        int r = m0 + row; int ss = r >> 5; int bb_ = r & 31;
        const unsigned short* src = embB + ((size_t)bb_ * S_ + ss) * E_ + k0 + ke;
        __builtin_amdgcn_global_load_lds((const __attribute__((address_space(1))) unsigned int*)src,
            (__attribute__((address_space(3))) unsigned int*)(As + chunk * 1024), 16, 0, 0);
      }
      { // B
        const unsigned short* src = Wd + (size_t)(n0 + row) * E_ + k0 + ke;
        __builtin_amdgcn_global_load_lds((const __attribute__((address_space(1))) unsigned int*)src,
            (__attribute__((address_space(3))) unsigned int*)(Bs + chunk * 1024), 16, 0, 0);
      }
    }
    asm volatile("s_waitcnt vmcnt(0)" ::: "memory");
    __syncthreads();

    short8 af[4], bfm[4];
    int kbyte = ((lane >> 4) * 8) * 2;
    #pragma unroll
    for (int mt = 0; mt < 4; ++mt) {
      int p = (mq + mt * 16 + (lane & 15)) * 64 + kbyte;
      int q = p ^ (((p >> 9) & 1) << 5);
      af[mt] = *(const short8*)(As + q);
    }
    #pragma unroll
    for (int nt = 0; nt < 4; ++nt) {
      int p = (nq + nt * 16 + (lane & 15)) * 64 + kbyte;
      int q = p ^ (((p >> 9) & 1) << 5);
      bfm[nt] = *(const short8*)(Bs + q);
    }
    #pragma unroll
    for (int mt = 0; mt < 4; ++mt)
      #pragma unroll
      for (int nt = 0; nt < 4; ++nt)
        acc[mt][nt] = __builtin_amdgcn_mfma_f32_16x16x32_bf16(af[mt], bfm[nt], acc[mt][nt], 0, 0, 0);
  }

  #pragma unroll
  for (int nt = 0; nt < 4; ++nt) {
    int col = n0 + nq + nt * 16 + (lane & 15);
    float bv = bias[col];
    #pragma unroll
    for (int mt = 0; mt < 4; ++mt) {
      int grow0 = m0 + mq + mt * 16 + (lane >> 4) * 4;
      #pragma unroll
      for (int r = 0; r < 4; ++r)
        G[((size_t)d * (S_ * B_) + grow0 + r) * G4 + col] = acc[mt][nt][r] + bv;
    }
  }
}

// ---------------- Persistent recurrent LSTM ------------------------------------------------
// 8 WGs x 512 threads: WG w -> dir d = w>>2, wi = w&3 owns h-indices [wi*96, wi*96+96).
// Wave q: gate g = q>>1, h-sub-block (q&1)*48. W_hh B-frags in registers.
// NO FENCES: h broadcast via sc0sc1 write-through stores + per-wave vmcnt(0) ack,
// monotonic relaxed-atomic barrier (no L2 writeback/invalidate => G stays cached).
__global__ __launch_bounds__(512) void lstm_rec(
    const unsigned short* __restrict__ WhhB,   // [2][1536][384] bf16
    const unsigned short* __restrict__ hinit,  // [2][32][384] bf16
    const float* __restrict__ c0,              // [2][32][384] fp32
    const float* __restrict__ G,               // [2][512*32][1536] fp32
    unsigned short* __restrict__ hall,         // [2][512][32][384] bf16
    unsigned* __restrict__ bar)                // per-dir: cnt @ d*128, gen @ d*128+32
{
  const int w   = blockIdx.x;        // 0..7
  const int d   = w >> 2;
  const int wi  = w & 3;
  const int j0  = wi * 96;
  const int tid = threadIdx.x, wave = tid >> 6, lane = tid & 63;
  const int g   = wave >> 1;
  const int hq  = (wave & 1) * 48;
  const int l15 = lane & 15, l4 = lane >> 4;

  __shared__ float g_lds[4][32][100];   // pad 100 (100%32=4) tames bank aliasing

  const int growbase = g * 384 + j0 + hq;   // + nt*16 + l15 = W_hh gate-row

  // B-fragments: row = gate-row, k = ks*32 + l4*8 + e
  short8 Bf[3][12];
  {
    const unsigned short* Wd = WhhB + (size_t)d * G4 * HH_;
    #pragma unroll
    for (int nt = 0; nt < 3; ++nt) {
      const unsigned short* rp = Wd + (size_t)(growbase + nt * 16 + l15) * HH_ + l4 * 8;
      #pragma unroll
      for (int ks = 0; ks < 12; ++ks)
        Bf[nt][ks] = *(const short8*)(rp + ks * 32);
    }
  }

  // update-phase ownership: thread tid<384 owns (batch up_b, 8 h-elems at up_j)
  const int up_b = tid / 12;
  const int up_j = (tid % 12) * 8;
  float c_reg[8];
  if (tid < 384) {
    #pragma unroll
    for (int e = 0; e < 8; ++e)
      c_reg[e] = c0[((size_t)d * B_ + up_b) * HH_ + j0 + up_j + e];
  }

  unsigned* cnt = bar + d * 128;
  unsigned* gen = bar + d * 128 + 32;

  // G prefetch for t=0
  float gp[2][3][4];
  {
    int s0 = d ? (S_ - 1) : 0;
    const float* Gs = G + (size_t)(d * S_ + s0) * B_ * G4;
    #pragma unroll
    for (int mt = 0; mt < 2; ++mt)
      #pragma unroll
      for (int nt = 0; nt < 3; ++nt)
        #pragma unroll
        for (int r = 0; r < 4; ++r)
          gp[mt][nt][r] = Gs[(size_t)(mt * 16 + l4 * 4 + r) * G4 + growbase + nt * 16 + l15];
  }
  __syncthreads();

  for (int t = 0; t < S_; ++t) {
    const int s = d ? (S_ - 1 - t) : t;
    const unsigned short* hsrc = (t == 0)
        ? (hinit + (size_t)d * B_ * HH_)
        : (hall + ((size_t)d * S_ + (d ? s + 1 : s - 1)) * B_ * HH_);

    f32x4 acc[2][3];
    #pragma unroll
    for (int mt = 0; mt < 2; ++mt)
      #pragma unroll
      for (int nt = 0; nt < 3; ++nt)
        #pragma unroll
        for (int r = 0; r < 4; ++r)
          acc[mt][nt][r] = gp[mt][nt][r];

    const int kb = l4 * 8;
    #pragma unroll
    for (int ks = 0; ks < 12; ++ks) {
      short8 a0 = *(const short8*)(hsrc + (size_t)l15 * HH_ + ks * 32 + kb);
      short8 a1 = *(const short8*)(hsrc + (size_t)(16 + l15) * HH_ + ks * 32 + kb);
      #pragma unroll
      for (int nt = 0; nt < 3; ++nt) {
        acc[0][nt] = __builtin_amdgcn_mfma_f32_16x16x32_bf16(a0, Bf[nt][ks], acc[0][nt], 0, 0, 0);
        acc[1][nt] = __builtin_amdgcn_mfma_f32_16x16x32_bf16(a1, Bf[nt][ks], acc[1][nt], 0, 0, 0);
      }
    }

    // gate exchange through LDS
    #pragma unroll
    for (int mt = 0; mt < 2; ++mt)
      #pragma unroll
      for (int nt = 0; nt < 3; ++nt)
        #pragma unroll
        for (int r = 0; r < 4; ++r)
          g_lds[g][mt * 16 + l4 * 4 + r][hq + nt * 16 + l15] = acc[mt][nt][r];
    __syncthreads();

    // G prefetch for t+1 (independent of h; latency overlaps update VALU + barrier)
    if (t + 1 < S_) {
      int s2 = d ? (S_ - 2 - t) : (t + 1);
      const float* Gs = G + (size_t)(d * S_ + s2) * B_ * G4;
      #pragma unroll
      for (int mt = 0; mt < 2; ++mt)
        #pragma unroll
        for (int nt = 0; nt < 3; ++nt)
          #pragma unroll
          for (int r = 0; r < 4; ++r)
            gp[mt][nt][r] = Gs[(size_t)(mt * 16 + l4 * 4 + r) * G4 + growbase + nt * 16 + l15];
    }

    // h/c update: thread owns (up_b, up_j..up_j+8); gates from LDS, c in registers,
    // h packed to bf16 and written through to coherence point (16B store)
    if (tid < 384) {
      float iv[8], fv[8], gv[8], ov[8];
      *(f32x4*)&iv[0] = *(const f32x4*)&g_lds[0][up_b][up_j];
      *(f32x4*)&iv[4] = *(const f32x4*)&g_lds[0][up_b][up_j + 4];
      *(f32x4*)&fv[0] = *(const f32x4*)&g_lds[1][up_b][up_j];
      *(f32x4*)&fv[4] = *(const f32x4*)&g_lds[1][up_b][up_j + 4];
      *(f32x4*)&gv[0] = *(const f32x4*)&g_lds[2][up_b][up_j];
      *(f32x4*)&gv[4] = *(const f32x4*)&g_lds[2][up_b][up_j + 4];
      *(f32x4*)&ov[0] = *(const f32x4*)&g_lds[3][up_b][up_j];
      *(f32x4*)&ov[4] = *(const f32x4*)&g_lds[3][up_b][up_j + 4];
      unsigned hw[4];
      #pragma unroll
      for (int e2 = 0; e2 < 4; ++e2) {
        unsigned lohi[2];
        #pragma unroll
        for (int k = 0; k < 2; ++k) {
          int e = e2 * 2 + k;
          float c = sigm(fv[e]) * c_reg[e] + sigm(iv[e]) * tanh_fast(gv[e]);
          float h = sigm(ov[e]) * tanh_fast(c);
          c_reg[e] = c;
          lohi[k] = (unsigned)f2bf(h);
        }
        hw[e2] = lohi[0] | (lohi[1] << 16);
      }
      void* pp = (void*)(hall + (((size_t)d * S_ + s) * B_ + up_b) * HH_ + j0 + up_j);
      store_b128_wt(pp, *(uint4v*)hw);
    }

    // ack all my stores (and gp loads) at the coherence point, then WG-rendezvous
    asm volatile("s_waitcnt vmcnt(0)" ::: "memory");
    __syncthreads();

    // 4-party per-direction device barrier: monotonic count, relaxed atomics only
    if (tid == 0) {
      unsigned a = __hip_atomic_fetch_add(cnt, 1u, __ATOMIC_RELAXED, __HIP_MEMORY_SCOPE_AGENT);
      if (a == (unsigned)(4 * t + 3)) {
        __hip_atomic_store(gen, (unsigned)(t + 1), __ATOMIC_RELAXED, __HIP_MEMORY_SCOPE_AGENT);
      } else {
        while (__hip_atomic_load(gen, __ATOMIC_RELAXED, __HIP_MEMORY_SCOPE_AGENT) < (unsigned)(t + 1)) {}
      }
    }
    __syncthreads();
  }
}

// ---------------- Logits: [b][s][17] = concat(hf,hb) @ W_tag^T + b_tag ---------------------
__global__ __launch_bounds__(256) void logits_k(
    const unsigned short* __restrict__ hall,
    const float* __restrict__ Wtag, const float* __restrict__ btag,
    float* __restrict__ logits)
{
  int gid = blockIdx.x * blockDim.x + threadIdx.x;
  if (gid >= B_ * S_ * NT) return;
  int n = gid % NT, bs = gid / NT;
  int b_ = bs / S_, s = bs - b_ * S_;
  const unsigned short* hf = hall + (((size_t)0 * S_ + s) * B_ + b_) * HH_;
  const unsigned short* hb = hall + (((size_t)1 * S_ + s) * B_ + b_) * HH_;
  const float* w0 = Wtag + (size_t)n * (2 * HH_);
  float acc = btag[n];
  for (int k = 0; k < HH_; k += 8) {
    short8 hv = *(const short8*)(hf + k);
    #pragma unroll
    for (int j = 0; j < 8; ++j) acc += bf2f((unsigned short)hv[j]) * w0[k + j];
  }
  for (int k = 0; k < HH_; k += 8) {
    short8 hv = *(const short8*)(hb + k);
    #pragma unroll
    for (int j = 0; j < 8; ++j) acc += bf2f((unsigned short)hv[j]) * w0[HH_ + k + j];
  }
  logits[((size_t)b_ * S_ + s) * NT + n] = acc;
}

// ---------------- Viterbi (faithful: lse alpha + argmax backpointers) ----------------------
__global__ __launch_bounds__(64) void viterbi(
    const float* __restrict__ logits,   // [32][512][17]
    const int* __restrict__ mask,       // [32][512]
    const float* __restrict__ trans,    // [17][17]
    float* __restrict__ out)            // [32] scores then [32][512] paths (as float)
{
  const int b = blockIdx.x;
  const int lane = threadIdx.x;
  __shared__ float tr[NT * NT];
  __shared__ float alpha[NT];
  __shared__ signed char bp[S_][NT];
  __shared__ int len_s;

  int cnt = 0;
  for (int t = lane; t < S_; t += 64) cnt += mask[(size_t)b * S_ + t];
  #pragma unroll
  for (int o = 32; o > 0; o >>= 1) cnt += __shfl_down(cnt, o);
  if (lane == 0) len_s = cnt;
  for (int i = lane; i < NT * NT; i += 64) tr[i] = trans[i];
  if (lane < NT) alpha[lane] = (lane == 15) ? 0.0f : -1000.0f;
  __syncthreads();
  const int len = len_s;
  const float* lg = logits + (size_t)b * S_ * NT;

  for (int t = 0; t < S_; ++t) {
    float na = 0.f; signed char am = 0;
    if (lane < NT) {
      float v[NT];
      float best = -3.4e38f; int arg = 0;
      #pragma unroll
      for (int p = 0; p < NT; ++p) {
        float x = alpha[p] + tr[p * NT + lane];
        v[p] = x;
        if (x > best) { best = x; arg = p; }   // strict > keeps first max (jnp.argmax)
      }
      float ssum = 0.f;
      #pragma unroll
      for (int p = 0; p < NT; ++p) ssum += __expf(v[p] - best);
      na = lg[t * NT + lane] + best + __logf(ssum);
      am = (signed char)arg;
    }
    __syncthreads();
    if (lane < NT) {
      if (t < len) alpha[lane] = na;
      bp[t][lane] = am;
    }
    __syncthreads();
  }

  if (lane == 0) {
    float fin[NT];
    float best = -3.4e38f; int arg = 0;
    #pragma unroll
    for (int n = 0; n < NT; ++n) {
      fin[n] = alpha[n] + tr[n * NT + 16];
      if (fin[n] > best) { best = fin[n]; arg = n; }
    }
    float ss = 0.f;
    #pragma unroll
    for (int n = 0; n < NT; ++n) ss += __expf(fin[n] - best);
    out[b] = best + __logf(ss);

    int tag = arg;
    float* po = out + B_ + (size_t)b * S_;
    for (int t = S_ - 1; t >= 0; --t) {
      int nt;
      if (t == len - 1) nt = arg;
      else if (t < len - 1) nt = bp[t + 1][tag];
      else nt = tag;
      tag = nt;
      po[t] = (t < len) ? (float)nt : -1.0f;
    }
  }
}

extern "C" void kernel_launch(void* const* d_in, const int* in_sizes, int n_in,
                              void* d_out, int out_size, void* d_ws, size_t ws_size,
                              hipStream_t stream) {
  const float* emb   = (const float*)d_in[0];
  const int*   maskp = (const int*)d_in[1];
  const float* h0    = (const float*)d_in[2];
  const float* c0    = (const float*)d_in[3];
  const float* Wihf  = (const float*)d_in[4];
  const float* Whhf  = (const float*)d_in[5];
  const float* bfp   = (const float*)d_in[6];
  const float* Wihb  = (const float*)d_in[7];
  const float* Whhb  = (const float*)d_in[8];
  const float* bbp   = (const float*)d_in[9];
  const float* Wtag  = (const float*)d_in[10];
  const float* btag  = (const float*)d_in[11];
  const float* trans = (const float*)d_in[12];
  float* out = (float*)d_out;

  char* ws = (char*)d_ws;
  const size_t szG    = (size_t)2 * S_ * B_ * G4 * 4;
  const size_t szEmb  = (size_t)B_ * S_ * E_ * 2;
  const size_t szWih  = (size_t)2 * G4 * E_ * 2;
  const size_t szWhh  = (size_t)2 * G4 * HH_ * 2;
  const size_t szHin  = (size_t)2 * B_ * HH_ * 2;
  const size_t szHall = (size_t)2 * S_ * B_ * HH_ * 2;
  const size_t szLog  = (size_t)B_ * S_ * NT * 4;

  size_t off = 0;
  float*          G      = (float*)(ws + off);          off += szG;
  unsigned short* embB   = (unsigned short*)(ws + off); off += szEmb;
  unsigned short* WihB   = (unsigned short*)(ws + off); off += szWih;
  unsigned short* WhhB   = (unsigned short*)(ws + off); off += szWhh;
  unsigned short* hinitB = (unsigned short*)(ws + off); off += szHin;
  unsigned short* hallB  = (unsigned short*)(ws + off); off += szHall;
  float*          logits = (float*)(ws + off);          off += szLog;
  unsigned*       bar    = (unsigned*)(ws + off);       off += 1024;
  if (ws_size < off) return;

  hipMemsetAsync(bar, 0, 1024, stream);

  cvt_bf16<<<2048, 256, 0, stream>>>(emb,  embB, B_ * S_ * E_);
  cvt_bf16<<<256, 256, 0, stream>>>(Wihf, WihB, G4 * E_);
  cvt_bf16<<<256, 256, 0, stream>>>(Wihb, WihB + (size_t)G4 * E_, G4 * E_);
  cvt_bf16<<<128, 256, 0, stream>>>(Whhf, WhhB, G4 * HH_);
  cvt_bf16<<<128, 256, 0, stream>>>(Whhb, WhhB + (size_t)G4 * HH_, G4 * HH_);
  cvt_bf16<<<48, 256, 0, stream>>>(h0, hinitB, 2 * B_ * HH_);

  gemm_input<<<dim3(G4 / 128, (S_ * B_) / 128, 2), 256, 0, stream>>>(embB, WihB, bfp, bbp, G);
  lstm_rec<<<8, 512, 0, stream>>>(WhhB, hinitB, c0, G, hallB, bar);
  logits_k<<<(B_ * S_ * NT + 255) / 256, 256, 0, stream>>>(hallB, Wtag, btag, logits);
  viterbi<<<B_, 64, 0, stream>>>(logits, maskp, trans, out);

  (void)in_sizes; (void)n_in; (void)out_size; (void)ws_size;
}

// Round 4
// 4801.950 us; speedup vs baseline: 1.5049x; 1.1725x over previous
//
#include <hip/hip_runtime.h>

#define B_  32
#define S_  512
#define E_  768
#define HH_ 384
#define G4  1536
#define NT  17

typedef __attribute__((ext_vector_type(8))) short short8;
typedef __attribute__((ext_vector_type(4))) float f32x4;
typedef __attribute__((ext_vector_type(4))) unsigned uint4v;
typedef __attribute__((ext_vector_type(4))) unsigned short ushort4v;

static __device__ __forceinline__ unsigned short f2bf(float x) {
  unsigned u = __float_as_uint(x);
  u = u + 0x7fffu + ((u >> 16) & 1u);
  return (unsigned short)(u >> 16);
}
static __device__ __forceinline__ float bf2f(unsigned short h) {
  return __uint_as_float(((unsigned)h) << 16);
}
static __device__ __forceinline__ float sigm(float x) {
  return 1.0f / (1.0f + __expf(-x));
}
static __device__ __forceinline__ float tanh_fast(float x) {
  float t = __expf(-2.0f * fabsf(x));
  float r = (1.0f - t) / (1.0f + t);   // stable: t<=1, no overflow
  return copysignf(r, x);
}
// write-through store to device coherence point (no dirty L2 => no fence/flush needed)
static __device__ __forceinline__ void store_b128_wt(void* p, uint4v v) {
  asm volatile("global_store_dwordx4 %0, %1, off sc0 sc1" :: "v"(p), "v"(v) : "memory");
}

__global__ __launch_bounds__(256) void cvt_bf16(const float* __restrict__ in,
                                                unsigned short* __restrict__ out, int n) {
  for (int i = blockIdx.x * blockDim.x + threadIdx.x; i < n; i += gridDim.x * blockDim.x)
    out[i] = f2bf(in[i]);
}

// ---------------- Input GEMM -> G2 (bf16, per-(s,wg) contiguous, frag-order) ---------------
// G2 block for (d,s,wi): [wave 8][mt 2][nt 3][l4 4][l15 16][r 4] ushort = 12288 elems (24 KB)
// so the lstm WG streams its whole per-step G slice as contiguous 512B-per-instr loads.
__global__ __launch_bounds__(256) void gemm_input(
    const unsigned short* __restrict__ embB,   // [32][512][768] bf16
    const unsigned short* __restrict__ WihB,   // [2][1536][768] bf16
    const float* __restrict__ bf, const float* __restrict__ bb,
    unsigned short* __restrict__ G2)
{
  const int d  = blockIdx.z;
  const int n0 = blockIdx.x * 128;
  const int m0 = blockIdx.y * 128;
  const unsigned short* Wd = WihB + (size_t)d * G4 * E_;
  const float* bias = d ? bb : bf;

  __shared__ char As[8192];
  __shared__ char Bs[8192];

  const int tid = threadIdx.x;
  const int wave = tid >> 6, lane = tid & 63;
  const int mq = (wave >> 1) * 64, nq = (wave & 1) * 64;
  const int l4g = lane >> 4, l15g = lane & 15;

  f32x4 acc[4][4] = {};

  for (int k0 = 0; k0 < E_; k0 += 32) {
    __syncthreads();
    #pragma unroll
    for (int i = 0; i < 2; ++i) {
      int chunk = wave * 2 + i;
      int p = chunk * 1024 + lane * 16;            // physical byte this lane fills
      int q = p ^ (((p >> 9) & 1) << 5);           // logical byte (st_16x32 involution)
      int row = q >> 6;                            // 0..127
      int ke  = (q & 63) >> 1;                     // bf16 element 0..31
      { // A: emb row (s*32+b ordering of the M dim)
        int r = m0 + row; int ss = r >> 5; int bb_ = r & 31;
        const unsigned short* src = embB + ((size_t)bb_ * S_ + ss) * E_ + k0 + ke;
        __builtin_amdgcn_global_load_lds((const __attribute__((address_space(1))) unsigned int*)src,
            (__attribute__((address_space(3))) unsigned int*)(As + chunk * 1024), 16, 0, 0);
      }
      { // B: W_ih rows
        const unsigned short* src = Wd + (size_t)(n0 + row) * E_ + k0 + ke;
        __builtin_amdgcn_global_load_lds((const __attribute__((address_space(1))) unsigned int*)src,
            (__attribute__((address_space(3))) unsigned int*)(Bs + chunk * 1024), 16, 0, 0);
      }
    }
    asm volatile("s_waitcnt vmcnt(0)" ::: "memory");
    __syncthreads();

    short8 af[4], bfm[4];
    int kbyte = ((lane >> 4) * 8) * 2;
    #pragma unroll
    for (int mt = 0; mt < 4; ++mt) {
      int p = (mq + mt * 16 + (lane & 15)) * 64 + kbyte;
      int q = p ^ (((p >> 9) & 1) << 5);
      af[mt] = *(const short8*)(As + q);
    }
    #pragma unroll
    for (int nt = 0; nt < 4; ++nt) {
      int p = (nq + nt * 16 + (lane & 15)) * 64 + kbyte;
      int q = p ^ (((p >> 9) & 1) << 5);
      bfm[nt] = *(const short8*)(Bs + q);
    }
    #pragma unroll
    for (int mt = 0; mt < 4; ++mt)
      #pragma unroll
      for (int nt = 0; nt < 4; ++nt)
        acc[mt][nt] = __builtin_amdgcn_mfma_f32_16x16x32_bf16(af[mt], bfm[nt], acc[mt][nt], 0, 0, 0);
  }

  // epilogue into G2 frag-order layout; pack 4 bf16 (r=0..3) per lane = 8B store, 512B/instr
  const int srow = (m0 + mq) >> 5;  // s constant per quadrant: batch = mt*16+l4g*4+r < 32
  #pragma unroll
  for (int nt = 0; nt < 4; ++nt) {
    int cb    = n0 + nq + nt * 16;          // lane-independent col base
    int gate  = cb / 384;
    int c384  = cb - gate * 384;
    int wi2   = c384 / 96;
    int c96   = c384 - wi2 * 96;
    int wavew = gate * 2 + (c96 / 48);
    int ntw   = (c96 % 48) / 16;
    float bv  = bias[cb + l15g];
    #pragma unroll
    for (int mt = 0; mt < 4; ++mt) {
      int mtw = (mt * 16) >> 4;             // batch/16 = mt (mt*16+l4g*4+r, r<4,l4g<4)
      unsigned short* dst = G2
          + ((((size_t)(d * S_ + srow) * 4 + wi2) * 8 + wavew) * 1536)
          + (size_t)(((mtw * 3 + ntw) * 4 + l4g) * 64 + l15g * 4);
      ushort4v v;
      #pragma unroll
      for (int r = 0; r < 4; ++r) v[r] = f2bf(acc[mt][nt][r] + bv);
      *(ushort4v*)dst = v;
    }
  }
}

// ---------------- Persistent recurrent LSTM ------------------------------------------------
// 8 WGs x 512 threads: WG w -> dir d = w>>2, wi = w&3 owns h-indices [wi*96, wi*96+96).
// Wave q: gate g = q>>1, h-sub-block (q&1)*48. W_hh B-frags pinned in registers (keep-alive).
// Bf indexed by LOCAL j (global ks = (3*wi+j)%12) so all register arrays are static-indexed;
// j<3 = own k-slice, served from LDS h (no coherence round-trip).
// Sync: per-WG monotonic flags (single-hop publish/poll), sc0sc1 write-through h + vmcnt ack.
__global__ __launch_bounds__(512, 2) void lstm_rec(
    const unsigned short* __restrict__ WhhB,   // [2][1536][384] bf16
    const unsigned short* __restrict__ hinit,  // [2][32][384] bf16
    const float* __restrict__ c0,              // [2][32][384] fp32
    const unsigned short* __restrict__ G2,     // frag-order bf16 (see gemm)
    unsigned short* __restrict__ hall,         // [2][512][32][384] bf16
    unsigned* __restrict__ bar)                // flag[d][wi] at (d*4+wi)*32 uints
{
  const int w   = blockIdx.x;        // 0..7
  const int d   = w >> 2;
  const int wi  = w & 3;
  const int j0  = wi * 96;
  const int tid = threadIdx.x, wave = tid >> 6, lane = tid & 63;
  const int g   = wave >> 1;
  const int hq  = (wave & 1) * 48;
  const int l15 = lane & 15, l4 = lane >> 4;

  __shared__ float g_lds[4][32][100];       // gate exchange (pad 100)
  __shared__ unsigned short h_lds[32][104]; // own h-slice [batch][96 + pad 8]

  const int growbase = g * 384 + j0 + hq;   // + nt*16 + l15 = W_hh gate-row

  // B-fragments, local-j order: Bf[nt][j] holds global k-step ksg=(3*wi+j)%12
  short8 Bf[3][12];
  {
    const unsigned short* Wd = WhhB + (size_t)d * G4 * HH_;
    #pragma unroll
    for (int nt = 0; nt < 3; ++nt) {
      const unsigned short* rp = Wd + (size_t)(growbase + nt * 16 + l15) * HH_ + l4 * 8;
      #pragma unroll
      for (int j = 0; j < 12; ++j) {
        int ksg = 3 * wi + j; if (ksg >= 12) ksg -= 12;
        Bf[nt][j] = *(const short8*)(rp + ksg * 32);
      }
    }
  }

  // update-phase ownership: thread tid<384 owns (batch up_b, 8 h-elems at local up_j)
  const int up_b = tid / 12;
  const int up_j = (tid % 12) * 8;          // local (0..95)
  float c_reg[8];
  if (tid < 384) {
    #pragma unroll
    for (int e = 0; e < 8; ++e)
      c_reg[e] = c0[((size_t)d * B_ + up_b) * HH_ + j0 + up_j + e];
    // prefill own h-slice LDS from hinit
    const unsigned short* hp = hinit + ((size_t)d * B_ + up_b) * HH_ + j0 + up_j;
    uint4v hv = *(const uint4v*)hp;
    *(uint4v*)(&h_lds[up_b][up_j]) = hv;
  }

  unsigned* myflag = bar + (size_t)(d * 4 + wi) * 32;

  // G prefetch for t=0 (frag-order contiguous: 6 x 8B per thread)
  ushort4v gpv[6];
  {
    int s0 = d ? (S_ - 1) : 0;
    const unsigned short* Gs = G2 + ((((size_t)(d * S_ + s0) * 4 + wi) * 8 + wave) * 1536);
    #pragma unroll
    for (int mt = 0; mt < 2; ++mt)
      #pragma unroll
      for (int nt = 0; nt < 3; ++nt)
        gpv[mt * 3 + nt] = *(const ushort4v*)(Gs + ((mt * 3 + nt) * 4 + l4) * 64 + l15 * 4);
  }
  __syncthreads();

  for (int t = 0; t < S_; ++t) {
    const int s = d ? (S_ - 1 - t) : t;

    // keep W_hh fragments pinned in registers across the loop
    #pragma unroll
    for (int nt = 0; nt < 3; ++nt) {
      asm volatile("" : "+v"(Bf[nt][0]), "+v"(Bf[nt][1]), "+v"(Bf[nt][2]), "+v"(Bf[nt][3]),
                         "+v"(Bf[nt][4]), "+v"(Bf[nt][5]));
      asm volatile("" : "+v"(Bf[nt][6]), "+v"(Bf[nt][7]), "+v"(Bf[nt][8]), "+v"(Bf[nt][9]),
                         "+v"(Bf[nt][10]), "+v"(Bf[nt][11]));
    }

    // acc init from prefetched G (bf16 -> f32)
    f32x4 acc[2][3];
    #pragma unroll
    for (int mt = 0; mt < 2; ++mt)
      #pragma unroll
      for (int nt = 0; nt < 3; ++nt) {
        ushort4v u = gpv[mt * 3 + nt];
        #pragma unroll
        for (int r = 0; r < 4; ++r) acc[mt][nt][r] = bf2f(u[r]);
      }

    const int kb = l4 * 8;

    // ---- own-slice MFMAs (j=0..2) from LDS h: no flags/coherence needed ----
    #pragma unroll
    for (int j = 0; j < 3; ++j) {
      short8 a0 = *(const short8*)(&h_lds[l15][j * 32 + kb]);
      short8 a1 = *(const short8*)(&h_lds[16 + l15][j * 32 + kb]);
      #pragma unroll
      for (int nt = 0; nt < 3; ++nt) {
        acc[0][nt] = __builtin_amdgcn_mfma_f32_16x16x32_bf16(a0, Bf[nt][j], acc[0][nt], 0, 0, 0);
        acc[1][nt] = __builtin_amdgcn_mfma_f32_16x16x32_bf16(a1, Bf[nt][j], acc[1][nt], 0, 0, 0);
      }
    }

    // ---- wait for other WGs' h of step t-1 (single-hop flag poll, 3 spare lanes) ----
    if (t > 0 && tid >= 448 && tid < 451) {
      int idx = tid - 448;
      int ow = idx + (idx >= wi);
      const unsigned* fp = bar + (size_t)(d * 4 + ow) * 32;
      while (__hip_atomic_load(fp, __ATOMIC_RELAXED, __HIP_MEMORY_SCOPE_AGENT) < (unsigned)t) {}
    }
    __syncthreads();

    // ---- others' slices (j=3..11) from global h ----
    const unsigned short* hsrc = (t == 0)
        ? (hinit + (size_t)d * B_ * HH_)
        : (hall + ((size_t)d * S_ + (d ? s + 1 : s - 1)) * B_ * HH_);
    #pragma unroll
    for (int j = 3; j < 12; ++j) {
      int ksg = 3 * wi + j; if (ksg >= 12) ksg -= 12;
      short8 a0 = *(const short8*)(hsrc + (size_t)l15 * HH_ + ksg * 32 + kb);
      short8 a1 = *(const short8*)(hsrc + (size_t)(16 + l15) * HH_ + ksg * 32 + kb);
      #pragma unroll
      for (int nt = 0; nt < 3; ++nt) {
        acc[0][nt] = __builtin_amdgcn_mfma_f32_16x16x32_bf16(a0, Bf[nt][j], acc[0][nt], 0, 0, 0);
        acc[1][nt] = __builtin_amdgcn_mfma_f32_16x16x32_bf16(a1, Bf[nt][j], acc[1][nt], 0, 0, 0);
      }
    }

    // ---- G prefetch for t+1 (issued here; completes during update+publish+next own-MFMA) --
    if (t + 1 < S_) {
      int s2 = d ? (S_ - 2 - t) : (t + 1);
      const unsigned short* Gs = G2 + ((((size_t)(d * S_ + s2) * 4 + wi) * 8 + wave) * 1536);
      #pragma unroll
      for (int mt = 0; mt < 2; ++mt)
        #pragma unroll
        for (int nt = 0; nt < 3; ++nt)
          gpv[mt * 3 + nt] = *(const ushort4v*)(Gs + ((mt * 3 + nt) * 4 + l4) * 64 + l15 * 4);
    }

    // ---- gate exchange through LDS ----
    #pragma unroll
    for (int mt = 0; mt < 2; ++mt)
      #pragma unroll
      for (int nt = 0; nt < 3; ++nt)
        #pragma unroll
        for (int r = 0; r < 4; ++r)
          g_lds[g][mt * 16 + l4 * 4 + r][hq + nt * 16 + l15] = acc[mt][nt][r];
    __syncthreads();

    // ---- h/c update; h -> LDS (own reuse) + write-through global (others) ----
    if (tid < 384) {
      float iv[8], fv[8], gv[8], ov[8];
      *(f32x4*)&iv[0] = *(const f32x4*)&g_lds[0][up_b][up_j];
      *(f32x4*)&iv[4] = *(const f32x4*)&g_lds[0][up_b][up_j + 4];
      *(f32x4*)&fv[0] = *(const f32x4*)&g_lds[1][up_b][up_j];
      *(f32x4*)&fv[4] = *(const f32x4*)&g_lds[1][up_b][up_j + 4];
      *(f32x4*)&gv[0] = *(const f32x4*)&g_lds[2][up_b][up_j];
      *(f32x4*)&gv[4] = *(const f32x4*)&g_lds[2][up_b][up_j + 4];
      *(f32x4*)&ov[0] = *(const f32x4*)&g_lds[3][up_b][up_j];
      *(f32x4*)&ov[4] = *(const f32x4*)&g_lds[3][up_b][up_j + 4];
      unsigned hw[4];
      #pragma unroll
      for (int e2 = 0; e2 < 4; ++e2) {
        unsigned lohi[2];
        #pragma unroll
        for (int k = 0; k < 2; ++k) {
          int e = e2 * 2 + k;
          float c = sigm(fv[e]) * c_reg[e] + sigm(iv[e]) * tanh_fast(gv[e]);
          float h = sigm(ov[e]) * tanh_fast(c);
          c_reg[e] = c;
          lohi[k] = (unsigned)f2bf(h);
        }
        hw[e2] = lohi[0] | (lohi[1] << 16);
      }
      uint4v hv = *(uint4v*)hw;
      *(uint4v*)(&h_lds[up_b][up_j]) = hv;   // own-slice reuse next step
      void* pp = (void*)(hall + (((size_t)d * S_ + s) * B_ + up_b) * HH_ + j0 + up_j);
      store_b128_wt(pp, hv);
      asm volatile("s_waitcnt vmcnt(0)" ::: "memory");  // ack write-through at coherence point
    }
    __syncthreads();

    // ---- single-hop publish: my h for step t is visible ----
    if (tid == 0)
      __hip_atomic_store(myflag, (unsigned)(t + 1), __ATOMIC_RELAXED, __HIP_MEMORY_SCOPE_AGENT);
  }
}

// ---------------- Logits: [b][s][17] = concat(hf,hb) @ W_tag^T + b_tag ---------------------
__global__ __launch_bounds__(256) void logits_k(
    const unsigned short* __restrict__ hall,
    const float* __restrict__ Wtag, const float* __restrict__ btag,
    float* __restrict__ logits)
{
  int gid = blockIdx.x * blockDim.x + threadIdx.x;
  if (gid >= B_ * S_ * NT) return;
  int n = gid % NT, bs = gid / NT;
  int b_ = bs / S_, s = bs - b_ * S_;
  const unsigned short* hf = hall + (((size_t)0 * S_ + s) * B_ + b_) * HH_;
  const unsigned short* hb = hall + (((size_t)1 * S_ + s) * B_ + b_) * HH_;
  const float* w0 = Wtag + (size_t)n * (2 * HH_);
  float acc = btag[n];
  for (int k = 0; k < HH_; k += 8) {
    short8 hv = *(const short8*)(hf + k);
    #pragma unroll
    for (int j = 0; j < 8; ++j) acc += bf2f((unsigned short)hv[j]) * w0[k + j];
  }
  for (int k = 0; k < HH_; k += 8) {
    short8 hv = *(const short8*)(hb + k);
    #pragma unroll
    for (int j = 0; j < 8; ++j) acc += bf2f((unsigned short)hv[j]) * w0[HH_ + k + j];
  }
  logits[((size_t)b_ * S_ + s) * NT + n] = acc;
}

// ---------------- Viterbi (faithful: lse alpha + argmax backpointers) ----------------------
__global__ __launch_bounds__(64) void viterbi(
    const float* __restrict__ logits,   // [32][512][17]
    const int* __restrict__ mask,       // [32][512]
    const float* __restrict__ trans,    // [17][17]
    float* __restrict__ out)            // [32] scores then [32][512] paths (as float)
{
  const int b = blockIdx.x;
  const int lane = threadIdx.x;
  __shared__ float tr[NT * NT];
  __shared__ float alpha[NT];
  __shared__ signed char bp[S_][NT];
  __shared__ int len_s;

  int cnt = 0;
  for (int t = lane; t < S_; t += 64) cnt += mask[(size_t)b * S_ + t];
  #pragma unroll
  for (int o = 32; o > 0; o >>= 1) cnt += __shfl_down(cnt, o);
  if (lane == 0) len_s = cnt;
  for (int i = lane; i < NT * NT; i += 64) tr[i] = trans[i];
  if (lane < NT) alpha[lane] = (lane == 15) ? 0.0f : -1000.0f;
  __syncthreads();
  const int len = len_s;
  const float* lg = logits + (size_t)b * S_ * NT;

  for (int t = 0; t < S_; ++t) {
    float na = 0.f; signed char am = 0;
    if (lane < NT) {
      float v[NT];
      float best = -3.4e38f; int arg = 0;
      #pragma unroll
      for (int p = 0; p < NT; ++p) {
        float x = alpha[p] + tr[p * NT + lane];
        v[p] = x;
        if (x > best) { best = x; arg = p; }   // strict > keeps first max (jnp.argmax)
      }
      float ssum = 0.f;
      #pragma unroll
      for (int p = 0; p < NT; ++p) ssum += __expf(v[p] - best);
      na = lg[t * NT + lane] + best + __logf(ssum);
      am = (signed char)arg;
    }
    __syncthreads();
    if (lane < NT) {
      if (t < len) alpha[lane] = na;
      bp[t][lane] = am;
    }
    __syncthreads();
  }

  if (lane == 0) {
    float fin[NT];
    float best = -3.4e38f; int arg = 0;
    #pragma unroll
    for (int n = 0; n < NT; ++n) {
      fin[n] = alpha[n] + tr[n * NT + 16];
      if (fin[n] > best) { best = fin[n]; arg = n; }
    }
    float ss = 0.f;
    #pragma unroll
    for (int n = 0; n < NT; ++n) ss += __expf(fin[n] - best);
    out[b] = best + __logf(ss);

    int tag = arg;
    float* po = out + B_ + (size_t)b * S_;
    for (int t = S_ - 1; t >= 0; --t) {
      int nt;
      if (t == len - 1) nt = arg;
      else if (t < len - 1) nt = bp[t + 1][tag];
      else nt = tag;
      tag = nt;
      po[t] = (t < len) ? (float)nt : -1.0f;
    }
  }
}

extern "C" void kernel_launch(void* const* d_in, const int* in_sizes, int n_in,
                              void* d_out, int out_size, void* d_ws, size_t ws_size,
                              hipStream_t stream) {
  const float* emb   = (const float*)d_in[0];
  const int*   maskp = (const int*)d_in[1];
  const float* h0    = (const float*)d_in[2];
  const float* c0    = (const float*)d_in[3];
  const float* Wihf  = (const float*)d_in[4];
  const float* Whhf  = (const float*)d_in[5];
  const float* bfp   = (const float*)d_in[6];
  const float* Wihb  = (const float*)d_in[7];
  const float* Whhb  = (const float*)d_in[8];
  const float* bbp   = (const float*)d_in[9];
  const float* Wtag  = (const float*)d_in[10];
  const float* btag  = (const float*)d_in[11];
  const float* trans = (const float*)d_in[12];
  float* out = (float*)d_out;

  char* ws = (char*)d_ws;
  const size_t szG2   = (size_t)2 * S_ * 4 * 12288 * 2;    // 100663296 (bf16 frag-order)
  const size_t szEmb  = (size_t)B_ * S_ * E_ * 2;
  const size_t szWih  = (size_t)2 * G4 * E_ * 2;
  const size_t szWhh  = (size_t)2 * G4 * HH_ * 2;
  const size_t szHin  = (size_t)2 * B_ * HH_ * 2;
  const size_t szHall = (size_t)2 * S_ * B_ * HH_ * 2;
  const size_t szLog  = (size_t)B_ * S_ * NT * 4;

  size_t off = 0;
  unsigned short* G2     = (unsigned short*)(ws + off); off += szG2;
  unsigned short* embB   = (unsigned short*)(ws + off); off += szEmb;
  unsigned short* WihB   = (unsigned short*)(ws + off); off += szWih;
  unsigned short* WhhB   = (unsigned short*)(ws + off); off += szWhh;
  unsigned short* hinitB = (unsigned short*)(ws + off); off += szHin;
  unsigned short* hallB  = (unsigned short*)(ws + off); off += szHall;
  float*          logits = (float*)(ws + off);          off += szLog;
  unsigned*       bar    = (unsigned*)(ws + off);       off += 1024;
  if (ws_size < off) return;

  hipMemsetAsync(bar, 0, 1024, stream);

  cvt_bf16<<<2048, 256, 0, stream>>>(emb,  embB, B_ * S_ * E_);
  cvt_bf16<<<256, 256, 0, stream>>>(Wihf, WihB, G4 * E_);
  cvt_bf16<<<256, 256, 0, stream>>>(Wihb, WihB + (size_t)G4 * E_, G4 * E_);
  cvt_bf16<<<128, 256, 0, stream>>>(Whhf, WhhB, G4 * HH_);
  cvt_bf16<<<128, 256, 0, stream>>>(Whhb, WhhB + (size_t)G4 * HH_, G4 * HH_);
  cvt_bf16<<<48, 256, 0, stream>>>(h0, hinitB, 2 * B_ * HH_);

  gemm_input<<<dim3(G4 / 128, (S_ * B_) / 128, 2), 256, 0, stream>>>(embB, WihB, bfp, bbp, G2);
  lstm_rec<<<8, 512, 0, stream>>>(WhhB, hinitB, c0, G2, hallB, bar);
  logits_k<<<(B_ * S_ * NT + 255) / 256, 256, 0, stream>>>(hallB, Wtag, btag, logits);
  viterbi<<<B_, 64, 0, stream>>>(logits, maskp, trans, out);

  (void)in_sizes; (void)n_in; (void)out_size; (void)ws_size;
}

// Round 5
// 3599.292 us; speedup vs baseline: 2.0077x; 1.3341x over previous
//
#include <hip/hip_runtime.h>

#define B_  32
#define S_  512
#define E_  768
#define HH_ 384
#define G4  1536
#define NT  17

typedef __attribute__((ext_vector_type(8))) short short8;
typedef __attribute__((ext_vector_type(4))) float f32x4;
typedef __attribute__((ext_vector_type(4))) unsigned uint4v;
typedef __attribute__((ext_vector_type(2))) unsigned uint2v;
typedef __attribute__((ext_vector_type(4))) unsigned short ushort4v;

static __device__ __forceinline__ unsigned short f2bf(float x) {
  unsigned u = __float_as_uint(x);
  u = u + 0x7fffu + ((u >> 16) & 1u);
  return (unsigned short)(u >> 16);
}
static __device__ __forceinline__ float bf2f(unsigned short h) {
  return __uint_as_float(((unsigned)h) << 16);
}
static __device__ __forceinline__ float sigm(float x) {
  return 1.0f / (1.0f + __expf(-x));
}
static __device__ __forceinline__ float tanh_fast(float x) {
  float t = __expf(-2.0f * fabsf(x));
  float r = (1.0f - t) / (1.0f + t);   // stable: t<=1, no overflow
  return copysignf(r, x);
}
// write-through stores to device coherence point (no dirty L2 => no fence/flush needed)
static __device__ __forceinline__ void store_b64_wt(void* p, uint2v v) {
  asm volatile("global_store_dwordx2 %0, %1, off sc0 sc1" :: "v"(p), "v"(v) : "memory");
}

__global__ __launch_bounds__(256) void cvt_bf16(const float* __restrict__ in,
                                                unsigned short* __restrict__ out, int n) {
  for (int i = blockIdx.x * blockDim.x + threadIdx.x; i < n; i += gridDim.x * blockDim.x)
    out[i] = f2bf(in[i]);
}

// ---------------- Input GEMM -> G2 (bf16, frag-order for the lstm consumer) ----------------
// G2 block for (d,s,wi,gate): [mt 2][nt 3][l4 4][l15 16][r 4] ushort = 1536 elems (3 KB).
// Block index = ((d*S+s)*8 + wi)*4 + gate.  (wi owns h-cols [wi*48, wi*48+48))
__global__ __launch_bounds__(256) void gemm_input(
    const unsigned short* __restrict__ embB,   // [32][512][768] bf16
    const unsigned short* __restrict__ WihB,   // [2][1536][768] bf16
    const float* __restrict__ bf, const float* __restrict__ bb,
    unsigned short* __restrict__ G2)
{
  const int d  = blockIdx.z;
  const int n0 = blockIdx.x * 128;
  const int m0 = blockIdx.y * 128;
  const unsigned short* Wd = WihB + (size_t)d * G4 * E_;
  const float* bias = d ? bb : bf;

  __shared__ char As[8192];
  __shared__ char Bs[8192];

  const int tid = threadIdx.x;
  const int wave = tid >> 6, lane = tid & 63;
  const int mq = (wave >> 1) * 64, nq = (wave & 1) * 64;
  const int l4g = lane >> 4, l15g = lane & 15;

  f32x4 acc[4][4] = {};

  for (int k0 = 0; k0 < E_; k0 += 32) {
    __syncthreads();
    #pragma unroll
    for (int i = 0; i < 2; ++i) {
      int chunk = wave * 2 + i;
      int p = chunk * 1024 + lane * 16;            // physical byte this lane fills
      int q = p ^ (((p >> 9) & 1) << 5);           // logical byte (st_16x32 involution)
      int row = q >> 6;                            // 0..127
      int ke  = (q & 63) >> 1;                     // bf16 element 0..31
      { // A: emb row (M ordering = s*32 + b)
        int r = m0 + row; int ss = r >> 5; int bb_ = r & 31;
        const unsigned short* src = embB + ((size_t)bb_ * S_ + ss) * E_ + k0 + ke;
        __builtin_amdgcn_global_load_lds((const __attribute__((address_space(1))) unsigned int*)src,
            (__attribute__((address_space(3))) unsigned int*)(As + chunk * 1024), 16, 0, 0);
      }
      { // B: W_ih rows
        const unsigned short* src = Wd + (size_t)(n0 + row) * E_ + k0 + ke;
        __builtin_amdgcn_global_load_lds((const __attribute__((address_space(1))) unsigned int*)src,
            (__attribute__((address_space(3))) unsigned int*)(Bs + chunk * 1024), 16, 0, 0);
      }
    }
    asm volatile("s_waitcnt vmcnt(0)" ::: "memory");
    __syncthreads();

    short8 af[4], bfm[4];
    int kbyte = ((lane >> 4) * 8) * 2;
    #pragma unroll
    for (int mt = 0; mt < 4; ++mt) {
      int p = (mq + mt * 16 + (lane & 15)) * 64 + kbyte;
      int q = p ^ (((p >> 9) & 1) << 5);
      af[mt] = *(const short8*)(As + q);
    }
    #pragma unroll
    for (int nt = 0; nt < 4; ++nt) {
      int p = (nq + nt * 16 + (lane & 15)) * 64 + kbyte;
      int q = p ^ (((p >> 9) & 1) << 5);
      bfm[nt] = *(const short8*)(Bs + q);
    }
    #pragma unroll
    for (int mt = 0; mt < 4; ++mt)
      #pragma unroll
      for (int nt = 0; nt < 4; ++nt)
        acc[mt][nt] = __builtin_amdgcn_mfma_f32_16x16x32_bf16(af[mt], bfm[nt], acc[mt][nt], 0, 0, 0);
  }

  // epilogue into G2 frag-order; M-quadrant covers TWO s values: s = srow + (mt>>1), b-row slot = mt&1
  const int srow = (m0 + mq) >> 5;   // even
  #pragma unroll
  for (int nt = 0; nt < 4; ++nt) {
    int cb    = n0 + nq + nt * 16;          // lane-independent col base
    int gate  = cb / 384;
    int c384  = cb - gate * 384;
    int wi2   = c384 / 48;
    int ntw   = (c384 - wi2 * 48) >> 4;     // 0..2
    float bv  = bias[cb + l15g];
    #pragma unroll
    for (int mt = 0; mt < 4; ++mt) {
      int s   = srow + (mt >> 1);
      int mtc = mt & 1;
      unsigned short* dst = G2
          + ((((size_t)(d * S_ + s) * 8 + wi2) * 4 + gate) * 1536)
          + (size_t)(((mtc * 3 + ntw) * 4 + l4g) * 64 + l15g * 4);
      ushort4v v;
      #pragma unroll
      for (int r = 0; r < 4; ++r) v[r] = f2bf(acc[mt][nt][r] + bv);
      *(ushort4v*)dst = v;
    }
  }
}

// ---------------- Persistent recurrent LSTM ------------------------------------------------
// 16 WGs x 512 threads: WG w -> dir d = w>>3, wi = w&7 owns h-cols [wi*48, wi*48+48).
// Wave q: gate g = q>>1, K-half kh = q&1 (k-steps kh*6..kh*6+5). W_hh frags = 18 short8 =
// 72 VGPR/lane (register-resident; the R4 144-VGPR layout spilled to L2-scratch per step).
// Two K-halves' partial accs summed during LDS gate-exchange read.
// Sync: per-WG monotonic flags, sc0sc1 write-through h, counted vmcnt(6) store-ack so the
// t+1 G2 prefetch stays in flight across the barrier.
__global__ __launch_bounds__(512, 2) void lstm_rec(
    const unsigned short* __restrict__ WhhB,   // [2][1536][384] bf16
    const unsigned short* __restrict__ hinit,  // [2][32][384] bf16
    const float* __restrict__ c0,              // [2][32][384] fp32
    const unsigned short* __restrict__ G2,     // frag-order bf16 (see gemm)
    unsigned short* __restrict__ hall,         // [2][512][32][384] bf16
    unsigned* __restrict__ bar)                // flag[d][wi] at (d*8+wi)*32 uints
{
  const int w   = blockIdx.x;        // 0..15
  const int d   = w >> 3;
  const int wi  = w & 7;
  const int j0  = wi * 48;
  const int tid = threadIdx.x, wave = tid >> 6, lane = tid & 63;
  const int g   = wave >> 1;
  const int kh  = wave & 1;
  const int l15 = lane & 15, l4 = lane >> 4;

  __shared__ float g_lds[4][2][32][52];      // [gate][khalf][batch][48 cols + pad 4]

  const int growbase = g * 384 + j0;         // + nt*16 + l15 = W_hh gate-row

  // B-fragments: Bf[nt][j] = W_hh row (growbase+nt*16+l15), k = (kh*6+j)*32 + l4*8
  short8 Bf[3][6];
  {
    const unsigned short* Wd = WhhB + (size_t)d * G4 * HH_;
    #pragma unroll
    for (int nt = 0; nt < 3; ++nt) {
      const unsigned short* rp = Wd + (size_t)(growbase + nt * 16 + l15) * HH_
                                    + (kh * 6) * 32 + l4 * 8;
      #pragma unroll
      for (int j = 0; j < 6; ++j)
        Bf[nt][j] = *(const short8*)(rp + j * 32);
    }
  }

  // update-phase ownership: thread tid<384 owns (batch up_b, 4 h-cols at local up_j)
  const int up_b = tid / 12;
  const int up_j = (tid % 12) * 4;           // local col 0..44
  float c_reg[4];
  if (tid < 384) {
    #pragma unroll
    for (int e = 0; e < 4; ++e)
      c_reg[e] = c0[((size_t)d * B_ + up_b) * HH_ + j0 + up_j + e];
  }

  unsigned* myflag = bar + (size_t)(d * 8 + wi) * 32;

  // G prefetch for t=0 (kh==0 waves only; kh==1 accumulates from zero)
  ushort4v gpv[6];
  if (kh == 0) {
    int s0 = d ? (S_ - 1) : 0;
    const unsigned short* Gs = G2 + ((((size_t)(d * S_ + s0) * 8 + wi) * 4 + g) * 1536);
    #pragma unroll
    for (int mt = 0; mt < 2; ++mt)
      #pragma unroll
      for (int nt = 0; nt < 3; ++nt)
        gpv[mt * 3 + nt] = *(const ushort4v*)(Gs + ((mt * 3 + nt) * 4 + l4) * 64 + l15 * 4);
  }
  __syncthreads();

  for (int t = 0; t < S_; ++t) {
    const int s = d ? (S_ - 1 - t) : t;

    // keep W_hh fragments live in registers across the loop
    #pragma unroll
    for (int nt = 0; nt < 3; ++nt)
      asm volatile("" : "+v"(Bf[nt][0]), "+v"(Bf[nt][1]), "+v"(Bf[nt][2]),
                        "+v"(Bf[nt][3]), "+v"(Bf[nt][4]), "+v"(Bf[nt][5]));

    // poll 7 peer flags for step t-1 (wave 7, lanes 0..6) — overlaps acc init
    if (t > 0 && wave == 7 && lane < 7) {
      int ow = lane + (lane >= wi);
      const unsigned* fp = bar + (size_t)(d * 8 + ow) * 32;
      while (__hip_atomic_load(fp, __ATOMIC_RELAXED, __HIP_MEMORY_SCOPE_AGENT) < (unsigned)t) {}
    }

    // acc init: kh0 from prefetched G2, kh1 from zero
    f32x4 acc[2][3];
    if (kh == 0) {
      #pragma unroll
      for (int mt = 0; mt < 2; ++mt)
        #pragma unroll
        for (int nt = 0; nt < 3; ++nt) {
          ushort4v u = gpv[mt * 3 + nt];
          #pragma unroll
          for (int r = 0; r < 4; ++r) acc[mt][nt][r] = bf2f(u[r]);
        }
    } else {
      #pragma unroll
      for (int mt = 0; mt < 2; ++mt)
        #pragma unroll
        for (int nt = 0; nt < 3; ++nt)
          #pragma unroll
          for (int r = 0; r < 4; ++r) acc[mt][nt][r] = 0.0f;
    }
    __syncthreads();   // h of step t-1 now published by all peers

    // A-frags from global h (write-through lines -> coherence point) + MFMAs
    const unsigned short* hsrc = (t == 0)
        ? (hinit + (size_t)d * B_ * HH_)
        : (hall + ((size_t)d * S_ + (d ? s + 1 : s - 1)) * B_ * HH_);
    const int kb = l4 * 8;
    #pragma unroll
    for (int j = 0; j < 6; ++j) {
      int ksg = kh * 6 + j;
      short8 a0 = *(const short8*)(hsrc + (size_t)l15 * HH_ + ksg * 32 + kb);
      short8 a1 = *(const short8*)(hsrc + (size_t)(16 + l15) * HH_ + ksg * 32 + kb);
      #pragma unroll
      for (int nt = 0; nt < 3; ++nt) {
        acc[0][nt] = __builtin_amdgcn_mfma_f32_16x16x32_bf16(a0, Bf[nt][j], acc[0][nt], 0, 0, 0);
        acc[1][nt] = __builtin_amdgcn_mfma_f32_16x16x32_bf16(a1, Bf[nt][j], acc[1][nt], 0, 0, 0);
      }
    }

    // gate exchange through LDS (both K-halves written; summed on read)
    #pragma unroll
    for (int mt = 0; mt < 2; ++mt)
      #pragma unroll
      for (int nt = 0; nt < 3; ++nt)
        #pragma unroll
        for (int r = 0; r < 4; ++r)
          g_lds[g][kh][mt * 16 + l4 * 4 + r][nt * 16 + l15] = acc[mt][nt][r];
    __syncthreads();

    // h/c update: 4 cols per thread; h write-through to global
    if (tid < 384) {
      f32x4 iv = *(const f32x4*)&g_lds[0][0][up_b][up_j] + *(const f32x4*)&g_lds[0][1][up_b][up_j];
      f32x4 fv = *(const f32x4*)&g_lds[1][0][up_b][up_j] + *(const f32x4*)&g_lds[1][1][up_b][up_j];
      f32x4 gv = *(const f32x4*)&g_lds[2][0][up_b][up_j] + *(const f32x4*)&g_lds[2][1][up_b][up_j];
      f32x4 ov = *(const f32x4*)&g_lds[3][0][up_b][up_j] + *(const f32x4*)&g_lds[3][1][up_b][up_j];
      unsigned hw[2];
      #pragma unroll
      for (int e2 = 0; e2 < 2; ++e2) {
        unsigned lohi[2];
        #pragma unroll
        for (int k = 0; k < 2; ++k) {
          int e = e2 * 2 + k;
          float c = sigm(fv[e]) * c_reg[e] + sigm(iv[e]) * tanh_fast(gv[e]);
          float h = sigm(ov[e]) * tanh_fast(c);
          c_reg[e] = c;
          lohi[k] = (unsigned)f2bf(h);
        }
        hw[e2] = lohi[0] | (lohi[1] << 16);
      }
      void* pp = (void*)(hall + (((size_t)d * S_ + s) * B_ + up_b) * HH_ + j0 + up_j);
      store_b64_wt(pp, *(uint2v*)hw);
    }

    // G2 prefetch for t+1 issued AFTER the store: counted vmcnt(6) acks only the store,
    // prefetch latency hides under the next flag poll + h loads
    if (kh == 0) {
      if (t + 1 < S_) {
        int s2 = d ? (S_ - 2 - t) : (t + 1);
        const unsigned short* Gs = G2 + ((((size_t)(d * S_ + s2) * 8 + wi) * 4 + g) * 1536);
        #pragma unroll
        for (int mt = 0; mt < 2; ++mt)
          #pragma unroll
          for (int nt = 0; nt < 3; ++nt)
            gpv[mt * 3 + nt] = *(const ushort4v*)(Gs + ((mt * 3 + nt) * 4 + l4) * 64 + l15 * 4);
        asm volatile("s_waitcnt vmcnt(6)" ::: "memory");
      } else {
        asm volatile("s_waitcnt vmcnt(0)" ::: "memory");
      }
    } else {
      asm volatile("s_waitcnt vmcnt(0)" ::: "memory");
    }
    __syncthreads();

    // single-hop publish: my h for step t is visible at the coherence point
    if (tid == 0)
      __hip_atomic_store(myflag, (unsigned)(t + 1), __ATOMIC_RELAXED, __HIP_MEMORY_SCOPE_AGENT);
  }
}

// ---------------- Logits: [b][s][17] = concat(hf,hb) @ W_tag^T + b_tag ---------------------
__global__ __launch_bounds__(256) void logits_k(
    const unsigned short* __restrict__ hall,
    const float* __restrict__ Wtag, const float* __restrict__ btag,
    float* __restrict__ logits)
{
  int gid = blockIdx.x * blockDim.x + threadIdx.x;
  if (gid >= B_ * S_ * NT) return;
  int n = gid % NT, bs = gid / NT;
  int b_ = bs / S_, s = bs - b_ * S_;
  const unsigned short* hf = hall + (((size_t)0 * S_ + s) * B_ + b_) * HH_;
  const unsigned short* hb = hall + (((size_t)1 * S_ + s) * B_ + b_) * HH_;
  const float* w0 = Wtag + (size_t)n * (2 * HH_);
  float acc = btag[n];
  for (int k = 0; k < HH_; k += 8) {
    short8 hv = *(const short8*)(hf + k);
    #pragma unroll
    for (int j = 0; j < 8; ++j) acc += bf2f((unsigned short)hv[j]) * w0[k + j];
  }
  for (int k = 0; k < HH_; k += 8) {
    short8 hv = *(const short8*)(hb + k);
    #pragma unroll
    for (int j = 0; j < 8; ++j) acc += bf2f((unsigned short)hv[j]) * w0[HH_ + k + j];
  }
  logits[((size_t)b_ * S_ + s) * NT + n] = acc;
}

// ---------------- Viterbi (faithful: lse alpha + argmax backpointers) ----------------------
__global__ __launch_bounds__(64) void viterbi(
    const float* __restrict__ logits,   // [32][512][17]
    const int* __restrict__ mask,       // [32][512]
    const float* __restrict__ trans,    // [17][17]
    float* __restrict__ out)            // [32] scores then [32][512] paths (as float)
{
  const int b = blockIdx.x;
  const int lane = threadIdx.x;
  __shared__ float tr[NT * NT];
  __shared__ float alpha[NT];
  __shared__ signed char bp[S_][NT];
  __shared__ int len_s;

  int cnt = 0;
  for (int t = lane; t < S_; t += 64) cnt += mask[(size_t)b * S_ + t];
  #pragma unroll
  for (int o = 32; o > 0; o >>= 1) cnt += __shfl_down(cnt, o);
  if (lane == 0) len_s = cnt;
  for (int i = lane; i < NT * NT; i += 64) tr[i] = trans[i];
  if (lane < NT) alpha[lane] = (lane == 15) ? 0.0f : -1000.0f;
  __syncthreads();
  const int len = len_s;
  const float* lg = logits + (size_t)b * S_ * NT;

  for (int t = 0; t < S_; ++t) {
    float na = 0.f; signed char am = 0;
    if (lane < NT) {
      float v[NT];
      float best = -3.4e38f; int arg = 0;
      #pragma unroll
      for (int p = 0; p < NT; ++p) {
        float x = alpha[p] + tr[p * NT + lane];
        v[p] = x;
        if (x > best) { best = x; arg = p; }   // strict > keeps first max (jnp.argmax)
      }
      float ssum = 0.f;
      #pragma unroll
      for (int p = 0; p < NT; ++p) ssum += __expf(v[p] - best);
      na = lg[t * NT + lane] + best + __logf(ssum);
      am = (signed char)arg;
    }
    __syncthreads();
    if (lane < NT) {
      if (t < len) alpha[lane] = na;
      bp[t][lane] = am;
    }
    __syncthreads();
  }

  if (lane == 0) {
    float fin[NT];
    float best = -3.4e38f; int arg = 0;
    #pragma unroll
    for (int n = 0; n < NT; ++n) {
      fin[n] = alpha[n] + tr[n * NT + 16];
      if (fin[n] > best) { best = fin[n]; arg = n; }
    }
    float ss = 0.f;
    #pragma unroll
    for (int n = 0; n < NT; ++n) ss += __expf(fin[n] - best);
    out[b] = best + __logf(ss);

    int tag = arg;
    float* po = out + B_ + (size_t)b * S_;
    for (int t = S_ - 1; t >= 0; --t) {
      int nt;
      if (t == len - 1) nt = arg;
      else if (t < len - 1) nt = bp[t + 1][tag];
      else nt = tag;
      tag = nt;
      po[t] = (t < len) ? (float)nt : -1.0f;
    }
  }
}

extern "C" void kernel_launch(void* const* d_in, const int* in_sizes, int n_in,
                              void* d_out, int out_size, void* d_ws, size_t ws_size,
                              hipStream_t stream) {
  const float* emb   = (const float*)d_in[0];
  const int*   maskp = (const int*)d_in[1];
  const float* h0    = (const float*)d_in[2];
  const float* c0    = (const float*)d_in[3];
  const float* Wihf  = (const float*)d_in[4];
  const float* Whhf  = (const float*)d_in[5];
  const float* bfp   = (const float*)d_in[6];
  const float* Wihb  = (const float*)d_in[7];
  const float* Whhb  = (const float*)d_in[8];
  const float* bbp   = (const float*)d_in[9];
  const float* Wtag  = (const float*)d_in[10];
  const float* btag  = (const float*)d_in[11];
  const float* trans = (const float*)d_in[12];
  float* out = (float*)d_out;

  char* ws = (char*)d_ws;
  const size_t szG2   = (size_t)2 * S_ * B_ * G4 * 2;      // 100663296 (bf16 frag-order)
  const size_t szEmb  = (size_t)B_ * S_ * E_ * 2;
  const size_t szWih  = (size_t)2 * G4 * E_ * 2;
  const size_t szWhh  = (size_t)2 * G4 * HH_ * 2;
  const size_t szHin  = (size_t)2 * B_ * HH_ * 2;
  const size_t szHall = (size_t)2 * S_ * B_ * HH_ * 2;
  const size_t szLog  = (size_t)B_ * S_ * NT * 4;

  size_t off = 0;
  unsigned short* G2     = (unsigned short*)(ws + off); off += szG2;
  unsigned short* embB   = (unsigned short*)(ws + off); off += szEmb;
  unsigned short* WihB   = (unsigned short*)(ws + off); off += szWih;
  unsigned short* WhhB   = (unsigned short*)(ws + off); off += szWhh;
  unsigned short* hinitB = (unsigned short*)(ws + off); off += szHin;
  unsigned short* hallB  = (unsigned short*)(ws + off); off += szHall;
  float*          logits = (float*)(ws + off);          off += szLog;
  unsigned*       bar    = (unsigned*)(ws + off);       off += 2048;
  if (ws_size < off) return;

  hipMemsetAsync(bar, 0, 2048, stream);

  cvt_bf16<<<2048, 256, 0, stream>>>(emb,  embB, B_ * S_ * E_);
  cvt_bf16<<<256, 256, 0, stream>>>(Wihf, WihB, G4 * E_);
  cvt_bf16<<<256, 256, 0, stream>>>(Wihb, WihB + (size_t)G4 * E_, G4 * E_);
  cvt_bf16<<<128, 256, 0, stream>>>(Whhf, WhhB, G4 * HH_);
  cvt_bf16<<<128, 256, 0, stream>>>(Whhb, WhhB + (size_t)G4 * HH_, G4 * HH_);
  cvt_bf16<<<48, 256, 0, stream>>>(h0, hinitB, 2 * B_ * HH_);

  gemm_input<<<dim3(G4 / 128, (S_ * B_) / 128, 2), 256, 0, stream>>>(embB, WihB, bfp, bbp, G2);
  lstm_rec<<<16, 512, 0, stream>>>(WhhB, hinitB, c0, G2, hallB, bar);
  logits_k<<<(B_ * S_ * NT + 255) / 256, 256, 0, stream>>>(hallB, Wtag, btag, logits);
  viterbi<<<B_, 64, 0, stream>>>(logits, maskp, trans, out);

  (void)in_sizes; (void)n_in; (void)out_size; (void)ws_size;
}

// Round 6
// 3514.700 us; speedup vs baseline: 2.0561x; 1.0241x over previous
//
#include <hip/hip_runtime.h>

#define B_  32
#define S_  512
#define E_  768
#define HH_ 384
#define G4  1536
#define NT  17

typedef __attribute__((ext_vector_type(8))) short short8;
typedef __attribute__((ext_vector_type(4))) float f32x4;
typedef __attribute__((ext_vector_type(4))) unsigned uint4v;
typedef __attribute__((ext_vector_type(2))) unsigned uint2v;
typedef __attribute__((ext_vector_type(4))) unsigned short ushort4v;

static __device__ __forceinline__ unsigned short f2bf(float x) {
  unsigned u = __float_as_uint(x);
  u = u + 0x7fffu + ((u >> 16) & 1u);
  return (unsigned short)(u >> 16);
}
static __device__ __forceinline__ float bf2f(unsigned short h) {
  return __uint_as_float(((unsigned)h) << 16);
}
static __device__ __forceinline__ float sigm(float x) {
  return 1.0f / (1.0f + __expf(-x));
}
static __device__ __forceinline__ float tanh_fast(float x) {
  float t = __expf(-2.0f * fabsf(x));
  float r = (1.0f - t) / (1.0f + t);   // stable: t<=1, no overflow
  return copysignf(r, x);
}
// write-through stores to device coherence point (no dirty L2 => no fence/flush needed)
static __device__ __forceinline__ void store_b64_wt(void* p, uint2v v) {
  asm volatile("global_store_dwordx2 %0, %1, off sc0 sc1" :: "v"(p), "v"(v) : "memory");
}

__global__ __launch_bounds__(256) void cvt_bf16(const float* __restrict__ in,
                                                unsigned short* __restrict__ out, int n) {
  for (int i = blockIdx.x * blockDim.x + threadIdx.x; i < n; i += gridDim.x * blockDim.x)
    out[i] = f2bf(in[i]);
}

// ---------------- Input GEMM -> G2 (bf16, frag-order for the lstm consumer) ----------------
// G2 block for (d,s,wi,gate): [mt 2][nt 3][l4 4][l15 16][r 4] ushort = 1536 elems (3 KB).
// Block index = ((d*S+s)*8 + wi)*4 + gate.  (wi owns h-cols [wi*48, wi*48+48))
__global__ __launch_bounds__(256) void gemm_input(
    const unsigned short* __restrict__ embB,   // [32][512][768] bf16
    const unsigned short* __restrict__ WihB,   // [2][1536][768] bf16
    const float* __restrict__ bf, const float* __restrict__ bb,
    unsigned short* __restrict__ G2)
{
  const int d  = blockIdx.z;
  const int n0 = blockIdx.x * 128;
  const int m0 = blockIdx.y * 128;
  const unsigned short* Wd = WihB + (size_t)d * G4 * E_;
  const float* bias = d ? bb : bf;

  __shared__ char As[8192];
  __shared__ char Bs[8192];

  const int tid = threadIdx.x;
  const int wave = tid >> 6, lane = tid & 63;
  const int mq = (wave >> 1) * 64, nq = (wave & 1) * 64;
  const int l4g = lane >> 4, l15g = lane & 15;

  f32x4 acc[4][4] = {};

  for (int k0 = 0; k0 < E_; k0 += 32) {
    __syncthreads();
    #pragma unroll
    for (int i = 0; i < 2; ++i) {
      int chunk = wave * 2 + i;
      int p = chunk * 1024 + lane * 16;            // physical byte this lane fills
      int q = p ^ (((p >> 9) & 1) << 5);           // logical byte (st_16x32 involution)
      int row = q >> 6;                            // 0..127
      int ke  = (q & 63) >> 1;                     // bf16 element 0..31
      { // A: emb row (M ordering = s*32 + b)
        int r = m0 + row; int ss = r >> 5; int bb_ = r & 31;
        const unsigned short* src = embB + ((size_t)bb_ * S_ + ss) * E_ + k0 + ke;
        __builtin_amdgcn_global_load_lds((const __attribute__((address_space(1))) unsigned int*)src,
            (__attribute__((address_space(3))) unsigned int*)(As + chunk * 1024), 16, 0, 0);
      }
      { // B: W_ih rows
        const unsigned short* src = Wd + (size_t)(n0 + row) * E_ + k0 + ke;
        __builtin_amdgcn_global_load_lds((const __attribute__((address_space(1))) unsigned int*)src,
            (__attribute__((address_space(3))) unsigned int*)(Bs + chunk * 1024), 16, 0, 0);
      }
    }
    asm volatile("s_waitcnt vmcnt(0)" ::: "memory");
    __syncthreads();

    short8 af[4], bfm[4];
    int kbyte = ((lane >> 4) * 8) * 2;
    #pragma unroll
    for (int mt = 0; mt < 4; ++mt) {
      int p = (mq + mt * 16 + (lane & 15)) * 64 + kbyte;
      int q = p ^ (((p >> 9) & 1) << 5);
      af[mt] = *(const short8*)(As + q);
    }
    #pragma unroll
    for (int nt = 0; nt < 4; ++nt) {
      int p = (nq + nt * 16 + (lane & 15)) * 64 + kbyte;
      int q = p ^ (((p >> 9) & 1) << 5);
      bfm[nt] = *(const short8*)(Bs + q);
    }
    #pragma unroll
    for (int mt = 0; mt < 4; ++mt)
      #pragma unroll
      for (int nt = 0; nt < 4; ++nt)
        acc[mt][nt] = __builtin_amdgcn_mfma_f32_16x16x32_bf16(af[mt], bfm[nt], acc[mt][nt], 0, 0, 0);
  }

  // epilogue into G2 frag-order; M-quadrant covers TWO s values: s = srow + (mt>>1), slot = mt&1
  const int srow = (m0 + mq) >> 5;   // even
  #pragma unroll
  for (int nt = 0; nt < 4; ++nt) {
    int cb    = n0 + nq + nt * 16;          // lane-independent col base
    int gate  = cb / 384;
    int c384  = cb - gate * 384;
    int wi2   = c384 / 48;
    int ntw   = (c384 - wi2 * 48) >> 4;     // 0..2
    float bv  = bias[cb + l15g];
    #pragma unroll
    for (int mt = 0; mt < 4; ++mt) {
      int s   = srow + (mt >> 1);
      int mtc = mt & 1;
      unsigned short* dst = G2
          + ((((size_t)(d * S_ + s) * 8 + wi2) * 4 + gate) * 1536)
          + (size_t)(((mtc * 3 + ntw) * 4 + l4g) * 64 + l15g * 4);
      ushort4v v;
      #pragma unroll
      for (int r = 0; r < 4; ++r) v[r] = f2bf(acc[mt][nt][r] + bv);
      *(ushort4v*)dst = v;
    }
  }
}

// ---------------- Persistent recurrent LSTM ------------------------------------------------
// 16 WGs x 512 threads: WG w -> dir d = w>>3, wi = w&7 owns h-cols [wi*48, wi*48+48).
// Wave q: gate g = q>>1, K-half kh = q&1. W_hh frags = 18 short8 = 72 VGPR (resident, R5).
// Changes vs R5: (1) G2 loads issued at TOP of step for the CURRENT s, consumed at the LDS
// exchange write (acc starts at 0) -> G2 latency hides under poll+h-load+MFMA, off the
// critical path. (2) every wave polls the 7 peer flags itself (lanes 0..6, divergent spin)
// -> the post-poll __syncthreads is gone; 2 barriers/step total (SYNCa, SYNCb).
__global__ __launch_bounds__(512, 2) void lstm_rec(
    const unsigned short* __restrict__ WhhB,   // [2][1536][384] bf16
    const unsigned short* __restrict__ hinit,  // [2][32][384] bf16
    const float* __restrict__ c0,              // [2][32][384] fp32
    const unsigned short* __restrict__ G2,     // frag-order bf16 (see gemm)
    unsigned short* __restrict__ hall,         // [2][512][32][384] bf16
    unsigned* __restrict__ bar)                // flag[d][wi] at (d*8+wi)*32 uints
{
  const int w   = blockIdx.x;        // 0..15
  const int d   = w >> 3;
  const int wi  = w & 7;
  const int j0  = wi * 48;
  const int tid = threadIdx.x, wave = tid >> 6, lane = tid & 63;
  const int g   = wave >> 1;
  const int kh  = wave & 1;
  const int l15 = lane & 15, l4 = lane >> 4;

  __shared__ float g_lds[4][2][32][52];      // [gate][khalf][batch][48 cols + pad 4]

  const int growbase = g * 384 + j0;         // + nt*16 + l15 = W_hh gate-row

  // B-fragments: Bf[nt][j] = W_hh row (growbase+nt*16+l15), k = (kh*6+j)*32 + l4*8
  short8 Bf[3][6];
  {
    const unsigned short* Wd = WhhB + (size_t)d * G4 * HH_;
    #pragma unroll
    for (int nt = 0; nt < 3; ++nt) {
      const unsigned short* rp = Wd + (size_t)(growbase + nt * 16 + l15) * HH_
                                    + (kh * 6) * 32 + l4 * 8;
      #pragma unroll
      for (int j = 0; j < 6; ++j)
        Bf[nt][j] = *(const short8*)(rp + j * 32);
    }
  }

  // update-phase ownership: thread tid<384 owns (batch up_b, 4 h-cols at local up_j)
  const int up_b = tid / 12;
  const int up_j = (tid % 12) * 4;           // local col 0..44
  float c_reg[4];
  if (tid < 384) {
    #pragma unroll
    for (int e = 0; e < 4; ++e)
      c_reg[e] = c0[((size_t)d * B_ + up_b) * HH_ + j0 + up_j + e];
  }

  unsigned* myflag = bar + (size_t)(d * 8 + wi) * 32;
  const unsigned* peer = bar;                // lanes 0..6: my peer's flag
  if (lane < 7) {
    int ow = lane + (lane >= wi);
    peer = bar + (size_t)(d * 8 + ow) * 32;
  }

  for (int t = 0; t < S_; ++t) {
    const int s = d ? (S_ - 1 - t) : t;

    // keep W_hh fragments live in registers across the loop
    #pragma unroll
    for (int nt = 0; nt < 3; ++nt)
      asm volatile("" : "+v"(Bf[nt][0]), "+v"(Bf[nt][1]), "+v"(Bf[nt][2]),
                        "+v"(Bf[nt][3]), "+v"(Bf[nt][4]), "+v"(Bf[nt][5]));

    // G2 loads for the CURRENT step, issued before the spin; consumed at exchange (~2us later)
    ushort4v gpv[6];
    if (kh == 0) {
      const unsigned short* Gs = G2 + ((((size_t)(d * S_ + s) * 8 + wi) * 4 + g) * 1536);
      #pragma unroll
      for (int mt = 0; mt < 2; ++mt)
        #pragma unroll
        for (int nt = 0; nt < 3; ++nt)
          gpv[mt * 3 + nt] = *(const ushort4v*)(Gs + ((mt * 3 + nt) * 4 + l4) * 64 + l15 * 4);
    }

    // every wave waits for the 7 peer flags itself (divergent spin, lanes 0..6)
    if (t > 0 && lane < 7) {
      while (__hip_atomic_load(peer, __ATOMIC_RELAXED, __HIP_MEMORY_SCOPE_AGENT)
             < (unsigned)t) {}
    }

    // h(t-1) loads + MFMAs, acc from zero (G2 folded in at exchange)
    f32x4 acc[2][3];
    #pragma unroll
    for (int mt = 0; mt < 2; ++mt)
      #pragma unroll
      for (int nt = 0; nt < 3; ++nt)
        #pragma unroll
        for (int r = 0; r < 4; ++r) acc[mt][nt][r] = 0.0f;

    const unsigned short* hsrc = (t == 0)
        ? (hinit + (size_t)d * B_ * HH_)
        : (hall + ((size_t)d * S_ + (d ? s + 1 : s - 1)) * B_ * HH_);
    const int kb = l4 * 8;
    #pragma unroll
    for (int j = 0; j < 6; ++j) {
      int ksg = kh * 6 + j;
      short8 a0 = *(const short8*)(hsrc + (size_t)l15 * HH_ + ksg * 32 + kb);
      short8 a1 = *(const short8*)(hsrc + (size_t)(16 + l15) * HH_ + ksg * 32 + kb);
      #pragma unroll
      for (int nt = 0; nt < 3; ++nt) {
        acc[0][nt] = __builtin_amdgcn_mfma_f32_16x16x32_bf16(a0, Bf[nt][j], acc[0][nt], 0, 0, 0);
        acc[1][nt] = __builtin_amdgcn_mfma_f32_16x16x32_bf16(a1, Bf[nt][j], acc[1][nt], 0, 0, 0);
      }
    }

    // gate exchange through LDS; kh0 adds the G2 pre-activation here
    if (kh == 0) {
      #pragma unroll
      for (int mt = 0; mt < 2; ++mt)
        #pragma unroll
        for (int nt = 0; nt < 3; ++nt) {
          ushort4v u = gpv[mt * 3 + nt];
          #pragma unroll
          for (int r = 0; r < 4; ++r)
            g_lds[g][0][mt * 16 + l4 * 4 + r][nt * 16 + l15] = acc[mt][nt][r] + bf2f(u[r]);
        }
    } else {
      #pragma unroll
      for (int mt = 0; mt < 2; ++mt)
        #pragma unroll
        for (int nt = 0; nt < 3; ++nt)
          #pragma unroll
          for (int r = 0; r < 4; ++r)
            g_lds[g][1][mt * 16 + l4 * 4 + r][nt * 16 + l15] = acc[mt][nt][r];
    }
    __syncthreads();   // SYNCa: g_lds writes -> update reads

    // h/c update: 4 cols per thread; h write-through to global + per-wave ack
    if (tid < 384) {
      f32x4 iv = *(const f32x4*)&g_lds[0][0][up_b][up_j] + *(const f32x4*)&g_lds[0][1][up_b][up_j];
      f32x4 fv = *(const f32x4*)&g_lds[1][0][up_b][up_j] + *(const f32x4*)&g_lds[1][1][up_b][up_j];
      f32x4 gv = *(const f32x4*)&g_lds[2][0][up_b][up_j] + *(const f32x4*)&g_lds[2][1][up_b][up_j];
      f32x4 ov = *(const f32x4*)&g_lds[3][0][up_b][up_j] + *(const f32x4*)&g_lds[3][1][up_b][up_j];
      unsigned hw[2];
      #pragma unroll
      for (int e2 = 0; e2 < 2; ++e2) {
        unsigned lohi[2];
        #pragma unroll
        for (int k = 0; k < 2; ++k) {
          int e = e2 * 2 + k;
          float c = sigm(fv[e]) * c_reg[e] + sigm(iv[e]) * tanh_fast(gv[e]);
          float h = sigm(ov[e]) * tanh_fast(c);
          c_reg[e] = c;
          lohi[k] = (unsigned)f2bf(h);
        }
        hw[e2] = lohi[0] | (lohi[1] << 16);
      }
      void* pp = (void*)(hall + (((size_t)d * S_ + s) * B_ + up_b) * HH_ + j0 + up_j);
      store_b64_wt(pp, *(uint2v*)hw);
      asm volatile("s_waitcnt vmcnt(0)" ::: "memory");  // ack h store at coherence point
    }
    __syncthreads();   // SYNCb: all stores acked; also orders update reads vs next g_lds write

    // single-hop publish: my h for step t is visible
    if (tid == 0)
      __hip_atomic_store(myflag, (unsigned)(t + 1), __ATOMIC_RELAXED, __HIP_MEMORY_SCOPE_AGENT);
  }
}

// ---------------- Logits: [b][s][17] = concat(hf,hb) @ W_tag^T + b_tag ---------------------
__global__ __launch_bounds__(256) void logits_k(
    const unsigned short* __restrict__ hall,
    const float* __restrict__ Wtag, const float* __restrict__ btag,
    float* __restrict__ logits)
{
  int gid = blockIdx.x * blockDim.x + threadIdx.x;
  if (gid >= B_ * S_ * NT) return;
  int n = gid % NT, bs = gid / NT;
  int b_ = bs / S_, s = bs - b_ * S_;
  const unsigned short* hf = hall + (((size_t)0 * S_ + s) * B_ + b_) * HH_;
  const unsigned short* hb = hall + (((size_t)1 * S_ + s) * B_ + b_) * HH_;
  const float* w0 = Wtag + (size_t)n * (2 * HH_);
  float acc = btag[n];
  for (int k = 0; k < HH_; k += 8) {
    short8 hv = *(const short8*)(hf + k);
    #pragma unroll
    for (int j = 0; j < 8; ++j) acc += bf2f((unsigned short)hv[j]) * w0[k + j];
  }
  for (int k = 0; k < HH_; k += 8) {
    short8 hv = *(const short8*)(hb + k);
    #pragma unroll
    for (int j = 0; j < 8; ++j) acc += bf2f((unsigned short)hv[j]) * w0[HH_ + k + j];
  }
  logits[((size_t)b_ * S_ + s) * NT + n] = acc;
}

// ---------------- Viterbi (faithful: lse alpha + argmax backpointers) ----------------------
// Logits staged in LDS up-front (f32x4 coalesced) so the 512-step serial loop never waits
// on global memory; transition column held in registers.
__global__ __launch_bounds__(64) void viterbi(
    const float* __restrict__ logits,   // [32][512][17]
    const int* __restrict__ mask,       // [32][512]
    const float* __restrict__ trans,    // [17][17]
    float* __restrict__ out)            // [32] scores then [32][512] paths (as float)
{
  const int b = blockIdx.x;
  const int lane = threadIdx.x;
  __shared__ float lgs[S_ * NT];        // 34816 B
  __shared__ float tr[NT * NT];
  __shared__ float alpha[NT];
  __shared__ signed char bp[S_][NT];
  __shared__ int len_s;

  // stage logits: 2176 f32x4 loads, 64 lanes
  {
    const f32x4* src4 = (const f32x4*)(logits + (size_t)b * S_ * NT);
    f32x4* dst4 = (f32x4*)lgs;
    for (int i = lane; i < (S_ * NT) / 4; i += 64) dst4[i] = src4[i];
  }
  int cnt = 0;
  for (int t = lane; t < S_; t += 64) cnt += mask[(size_t)b * S_ + t];
  #pragma unroll
  for (int o = 32; o > 0; o >>= 1) cnt += __shfl_down(cnt, o);
  if (lane == 0) len_s = cnt;
  for (int i = lane; i < NT * NT; i += 64) tr[i] = trans[i];
  if (lane < NT) alpha[lane] = (lane == 15) ? 0.0f : -1000.0f;
  __syncthreads();
  const int len = len_s;

  float trc[NT];   // my incoming-transition column: trc[p] = trans[p][lane]
  if (lane < NT) {
    #pragma unroll
    for (int p = 0; p < NT; ++p) trc[p] = tr[p * NT + lane];
  }

  for (int t = 0; t < S_; ++t) {
    float na = 0.f; signed char am = 0;
    if (lane < NT) {
      float v[NT];
      float best = -3.4e38f; int arg = 0;
      #pragma unroll
      for (int p = 0; p < NT; ++p) {
        float x = alpha[p] + trc[p];
        v[p] = x;
        if (x > best) { best = x; arg = p; }   // strict > keeps first max (jnp.argmax)
      }
      float ssum = 0.f;
      #pragma unroll
      for (int p = 0; p < NT; ++p) ssum += __expf(v[p] - best);
      na = lgs[t * NT + lane] + best + __logf(ssum);
      am = (signed char)arg;
    }
    __syncthreads();
    if (lane < NT) {
      if (t < len) alpha[lane] = na;
      bp[t][lane] = am;
    }
    __syncthreads();
  }

  if (lane == 0) {
    float fin[NT];
    float best = -3.4e38f; int arg = 0;
    #pragma unroll
    for (int n = 0; n < NT; ++n) {
      fin[n] = alpha[n] + tr[n * NT + 16];
      if (fin[n] > best) { best = fin[n]; arg = n; }
    }
    float ss = 0.f;
    #pragma unroll
    for (int n = 0; n < NT; ++n) ss += __expf(fin[n] - best);
    out[b] = best + __logf(ss);

    int tag = arg;
    float* po = out + B_ + (size_t)b * S_;
    for (int t = S_ - 1; t >= 0; --t) {
      int nt;
      if (t == len - 1) nt = arg;
      else if (t < len - 1) nt = bp[t + 1][tag];
      else nt = tag;
      tag = nt;
      po[t] = (t < len) ? (float)nt : -1.0f;
    }
  }
}

extern "C" void kernel_launch(void* const* d_in, const int* in_sizes, int n_in,
                              void* d_out, int out_size, void* d_ws, size_t ws_size,
                              hipStream_t stream) {
  const float* emb   = (const float*)d_in[0];
  const int*   maskp = (const int*)d_in[1];
  const float* h0    = (const float*)d_in[2];
  const float* c0    = (const float*)d_in[3];
  const float* Wihf  = (const float*)d_in[4];
  const float* Whhf  = (const float*)d_in[5];
  const float* bfp   = (const float*)d_in[6];
  const float* Wihb  = (const float*)d_in[7];
  const float* Whhb  = (const float*)d_in[8];
  const float* bbp   = (const float*)d_in[9];
  const float* Wtag  = (const float*)d_in[10];
  const float* btag  = (const float*)d_in[11];
  const float* trans = (const float*)d_in[12];
  float* out = (float*)d_out;

  char* ws = (char*)d_ws;
  const size_t szG2   = (size_t)2 * S_ * B_ * G4 * 2;      // 100663296 (bf16 frag-order)
  const size_t szEmb  = (size_t)B_ * S_ * E_ * 2;
  const size_t szWih  = (size_t)2 * G4 * E_ * 2;
  const size_t szWhh  = (size_t)2 * G4 * HH_ * 2;
  const size_t szHin  = (size_t)2 * B_ * HH_ * 2;
  const size_t szHall = (size_t)2 * S_ * B_ * HH_ * 2;
  const size_t szLog  = (size_t)B_ * S_ * NT * 4;

  size_t off = 0;
  unsigned short* G2     = (unsigned short*)(ws + off); off += szG2;
  unsigned short* embB   = (unsigned short*)(ws + off); off += szEmb;
  unsigned short* WihB   = (unsigned short*)(ws + off); off += szWih;
  unsigned short* WhhB   = (unsigned short*)(ws + off); off += szWhh;
  unsigned short* hinitB = (unsigned short*)(ws + off); off += szHin;
  unsigned short* hallB  = (unsigned short*)(ws + off); off += szHall;
  float*          logits = (float*)(ws + off);          off += szLog;
  unsigned*       bar    = (unsigned*)(ws + off);       off += 2048;
  if (ws_size < off) return;

  hipMemsetAsync(bar, 0, 2048, stream);

  cvt_bf16<<<2048, 256, 0, stream>>>(emb,  embB, B_ * S_ * E_);
  cvt_bf16<<<256, 256, 0, stream>>>(Wihf, WihB, G4 * E_);
  cvt_bf16<<<256, 256, 0, stream>>>(Wihb, WihB + (size_t)G4 * E_, G4 * E_);
  cvt_bf16<<<128, 256, 0, stream>>>(Whhf, WhhB, G4 * HH_);
  cvt_bf16<<<128, 256, 0, stream>>>(Whhb, WhhB + (size_t)G4 * HH_, G4 * HH_);
  cvt_bf16<<<48, 256, 0, stream>>>(h0, hinitB, 2 * B_ * HH_);

  gemm_input<<<dim3(G4 / 128, (S_ * B_) / 128, 2), 256, 0, stream>>>(embB, WihB, bfp, bbp, G2);
  lstm_rec<<<16, 512, 0, stream>>>(WhhB, hinitB, c0, G2, hallB, bar);
  logits_k<<<(B_ * S_ * NT + 255) / 256, 256, 0, stream>>>(hallB, Wtag, btag, logits);
  viterbi<<<B_, 64, 0, stream>>>(logits, maskp, trans, out);

  (void)in_sizes; (void)n_in; (void)out_size; (void)ws_size;
}

// Round 8
// 3487.943 us; speedup vs baseline: 2.0718x; 1.0077x over previous
//
#include <hip/hip_runtime.h>

#define B_  32
#define S_  512
#define E_  768
#define HH_ 384
#define G4  1536
#define NT  17

typedef __attribute__((ext_vector_type(8))) short short8;
typedef __attribute__((ext_vector_type(4))) float f32x4;
typedef __attribute__((ext_vector_type(4))) unsigned uint4v;
typedef __attribute__((ext_vector_type(2))) unsigned uint2v;
typedef __attribute__((ext_vector_type(4))) unsigned short ushort4v;

#define SENT 0x7F7F7F7Fu

static __device__ __forceinline__ unsigned short f2bf(float x) {
  unsigned u = __float_as_uint(x);
  u = u + 0x7fffu + ((u >> 16) & 1u);
  return (unsigned short)(u >> 16);
}
static __device__ __forceinline__ float bf2f(unsigned short h) {
  return __uint_as_float(((unsigned)h) << 16);
}
static __device__ __forceinline__ float sigm(float x) {
  return 1.0f / (1.0f + __expf(-x));
}
static __device__ __forceinline__ float tanh_fast(float x) {
  float t = __expf(-2.0f * fabsf(x));
  float r = (1.0f - t) / (1.0f + t);   // stable: t<=1, no overflow
  return copysignf(r, x);
}
// write-through stores to device coherence point (no dirty L2 => no fence/flush needed)
static __device__ __forceinline__ void store_b64_wt(void* p, uint2v v) {
  asm volatile("global_store_dwordx2 %0, %1, off sc0 sc1" :: "v"(p), "v"(v) : "memory");
}

__global__ __launch_bounds__(256) void cvt_bf16(const float* __restrict__ in,
                                                unsigned short* __restrict__ out, int n) {
  for (int i = blockIdx.x * blockDim.x + threadIdx.x; i < n; i += gridDim.x * blockDim.x)
    out[i] = f2bf(in[i]);
}

// ---------------- Input GEMM -> G2 (bf16, frag-order for the lstm consumer) ----------------
// G2 block for (d,s,wi,gate): [mt 2][nt 3][l4 4][l15 16][r 4] ushort = 1536 elems (3 KB).
// Block index = ((d*S+s)*8 + wi)*4 + gate.  (wi owns h-cols [wi*48, wi*48+48))
__global__ __launch_bounds__(256) void gemm_input(
    const unsigned short* __restrict__ embB,   // [32][512][768] bf16
    const unsigned short* __restrict__ WihB,   // [2][1536][768] bf16
    const float* __restrict__ bf, const float* __restrict__ bb,
    unsigned short* __restrict__ G2)
{
  const int d  = blockIdx.z;
  const int n0 = blockIdx.x * 128;
  const int m0 = blockIdx.y * 128;
  const unsigned short* Wd = WihB + (size_t)d * G4 * E_;
  const float* bias = d ? bb : bf;

  __shared__ char As[8192];
  __shared__ char Bs[8192];

  const int tid = threadIdx.x;
  const int wave = tid >> 6, lane = tid & 63;
  const int mq = (wave >> 1) * 64, nq = (wave & 1) * 64;
  const int l4g = lane >> 4, l15g = lane & 15;

  f32x4 acc[4][4] = {};

  for (int k0 = 0; k0 < E_; k0 += 32) {
    __syncthreads();
    #pragma unroll
    for (int i = 0; i < 2; ++i) {
      int chunk = wave * 2 + i;
      int p = chunk * 1024 + lane * 16;            // physical byte this lane fills
      int q = p ^ (((p >> 9) & 1) << 5);           // logical byte (st_16x32 involution)
      int row = q >> 6;                            // 0..127
      int ke  = (q & 63) >> 1;                     // bf16 element 0..31
      { // A: emb row (M ordering = s*32 + b)
        int r = m0 + row; int ss = r >> 5; int bb_ = r & 31;
        const unsigned short* src = embB + ((size_t)bb_ * S_ + ss) * E_ + k0 + ke;
        __builtin_amdgcn_global_load_lds((const __attribute__((address_space(1))) unsigned int*)src,
            (__attribute__((address_space(3))) unsigned int*)(As + chunk * 1024), 16, 0, 0);
      }
      { // B: W_ih rows
        const unsigned short* src = Wd + (size_t)(n0 + row) * E_ + k0 + ke;
        __builtin_amdgcn_global_load_lds((const __attribute__((address_space(1))) unsigned int*)src,
            (__attribute__((address_space(3))) unsigned int*)(Bs + chunk * 1024), 16, 0, 0);
      }
    }
    asm volatile("s_waitcnt vmcnt(0)" ::: "memory");
    __syncthreads();

    short8 af[4], bfm[4];
    int kbyte = ((lane >> 4) * 8) * 2;
    #pragma unroll
    for (int mt = 0; mt < 4; ++mt) {
      int p = (mq + mt * 16 + (lane & 15)) * 64 + kbyte;
      int q = p ^ (((p >> 9) & 1) << 5);
      af[mt] = *(const short8*)(As + q);
    }
    #pragma unroll
    for (int nt = 0; nt < 4; ++nt) {
      int p = (nq + nt * 16 + (lane & 15)) * 64 + kbyte;
      int q = p ^ (((p >> 9) & 1) << 5);
      bfm[nt] = *(const short8*)(Bs + q);
    }
    #pragma unroll
    for (int mt = 0; mt < 4; ++mt)
      #pragma unroll
      for (int nt = 0; nt < 4; ++nt)
        acc[mt][nt] = __builtin_amdgcn_mfma_f32_16x16x32_bf16(af[mt], bfm[nt], acc[mt][nt], 0, 0, 0);
  }

  // epilogue into G2 frag-order; M-quadrant covers TWO s values: s = srow + (mt>>1), slot = mt&1
  const int srow = (m0 + mq) >> 5;   // even
  #pragma unroll
  for (int nt = 0; nt < 4; ++nt) {
    int cb    = n0 + nq + nt * 16;          // lane-independent col base
    int gate  = cb / 384;
    int c384  = cb - gate * 384;
    int wi2   = c384 / 48;
    int ntw   = (c384 - wi2 * 48) >> 4;     // 0..2
    float bv  = bias[cb + l15g];
    #pragma unroll
    for (int mt = 0; mt < 4; ++mt) {
      int s   = srow + (mt >> 1);
      int mtc = mt & 1;
      unsigned short* dst = G2
          + ((((size_t)(d * S_ + s) * 8 + wi2) * 4 + gate) * 1536)
          + (size_t)(((mtc * 3 + ntw) * 4 + l4g) * 64 + l15g * 4);
      ushort4v v;
      #pragma unroll
      for (int r = 0; r < 4; ++r) v[r] = f2bf(acc[mt][nt][r] + bv);
      *(ushort4v*)dst = v;
    }
  }
}

// ---------------- Persistent recurrent LSTM ------------------------------------------------
// 16 WGs x 512 threads: WG w -> dir d = w>>3, wi = w&7 owns h-cols [wi*48, wi*48+48).
// Wave q: gate g = q>>1, K-half kh = q&1. W_hh frags = 18 short8 (register-resident).
// Sync: NO flags. hall is 0x7F-poisoned each call; consumers poll their h fragments with
// COHERENCE-POINT loads (sc0 sc1 - bypass L1/L2, required: plain loads cache the stale
// sentinel line forever since remote write-throughs never invalidate local L2 -> R7 hang).
// Producer's last action is the sc0 sc1 write-through store - no ack, no publish. Barriers
// are raw s_barrier + lgkmcnt only, so the mid-step G2 prefetch is never force-drained by
// a barrier (only by the poll's own vmcnt(0), after ~a full step of cover).
__global__ __launch_bounds__(512, 2) void lstm_rec(
    const unsigned short* __restrict__ WhhB,   // [2][1536][384] bf16
    const unsigned short* __restrict__ hinit,  // [2][32][384] bf16
    const float* __restrict__ c0,              // [2][32][384] fp32
    const unsigned short* __restrict__ G2,     // frag-order bf16 (see gemm)
    unsigned short* __restrict__ hall)         // [2][512][32][384] bf16, 0x7F-poisoned
{
  const int w   = blockIdx.x;        // 0..15
  const int d   = w >> 3;
  const int wi  = w & 7;
  const int j0  = wi * 48;
  const int tid = threadIdx.x, wave = tid >> 6, lane = tid & 63;
  const int g   = wave >> 1;
  const int kh  = wave & 1;
  const int l15 = lane & 15, l4 = lane >> 4;

  __shared__ float g_lds[4][2][32][52];      // [gate][khalf][batch][48 cols + pad 4]

  const int growbase = g * 384 + j0;         // + nt*16 + l15 = W_hh gate-row

  // B-fragments: Bf[nt][j] = W_hh row (growbase+nt*16+l15), k = (kh*6+j)*32 + l4*8
  short8 Bf[3][6];
  {
    const unsigned short* Wd = WhhB + (size_t)d * G4 * HH_;
    #pragma unroll
    for (int nt = 0; nt < 3; ++nt) {
      const unsigned short* rp = Wd + (size_t)(growbase + nt * 16 + l15) * HH_
                                    + (kh * 6) * 32 + l4 * 8;
      #pragma unroll
      for (int j = 0; j < 6; ++j)
        Bf[nt][j] = *(const short8*)(rp + j * 32);
    }
  }

  // update-phase ownership: thread tid<384 owns (batch up_b, 4 h-cols at local up_j)
  const int up_b = tid / 12;
  const int up_j = (tid % 12) * 4;           // local col 0..44
  float c_reg[4];
  if (tid < 384) {
    #pragma unroll
    for (int e = 0; e < 4; ++e)
      c_reg[e] = c0[((size_t)d * B_ + up_b) * HH_ + j0 + up_j + e];
  }

  // G2 for t=0
  ushort4v gpv[6];
  if (kh == 0) {
    int s0 = d ? (S_ - 1) : 0;
    const unsigned short* Gs = G2 + ((((size_t)(d * S_ + s0) * 8 + wi) * 4 + g) * 1536);
    #pragma unroll
    for (int mt = 0; mt < 2; ++mt)
      #pragma unroll
      for (int nt = 0; nt < 3; ++nt)
        gpv[mt * 3 + nt] = *(const ushort4v*)(Gs + ((mt * 3 + nt) * 4 + l4) * 64 + l15 * 4);
  }
  __syncthreads();

  for (int t = 0; t < S_; ++t) {
    const int s = d ? (S_ - 1 - t) : t;

    // keep W_hh fragments live in registers across the loop
    #pragma unroll
    for (int nt = 0; nt < 3; ++nt)
      asm volatile("" : "+v"(Bf[nt][0]), "+v"(Bf[nt][1]), "+v"(Bf[nt][2]),
                        "+v"(Bf[nt][3]), "+v"(Bf[nt][4]), "+v"(Bf[nt][5]));

    // ---- h(t-1): poll-load 12 fragments with sc0 sc1 (bypass caches); data = its own flag --
    const unsigned short* hsrc = (t == 0)
        ? (hinit + (size_t)d * B_ * HH_)
        : (hall + ((size_t)d * S_ + (d ? s + 1 : s - 1)) * B_ * HH_);
    const int kb = l4 * 8;
    uint4v f0[6], f1[6];
    const bool chk = (t > 0);
    while (true) {
      #pragma unroll
      for (int j = 0; j < 6; ++j) {
        const unsigned short* p0 = hsrc + (size_t)l15 * HH_ + (kh * 6 + j) * 32 + kb;
        const unsigned short* p1 = hsrc + (size_t)(16 + l15) * HH_ + (kh * 6 + j) * 32 + kb;
        asm volatile("global_load_dwordx4 %0, %1, off sc0 sc1" : "=v"(f0[j]) : "v"(p0) : "memory");
        asm volatile("global_load_dwordx4 %0, %1, off sc0 sc1" : "=v"(f1[j]) : "v"(p1) : "memory");
      }
      asm volatile("s_waitcnt vmcnt(0)" ::: "memory");
      __builtin_amdgcn_sched_barrier(0);
      if (!chk) break;
      unsigned bad = 0;
      #pragma unroll
      for (int j = 0; j < 6; ++j)
        #pragma unroll
        for (int k2 = 0; k2 < 4; ++k2)
          bad |= (unsigned)(f0[j][k2] == SENT) | (unsigned)(f1[j][k2] == SENT);
      if (!__any((int)bad)) break;
    }

    // ---- MFMAs (acc from zero; G2 folded in at exchange) ----
    f32x4 acc[2][3];
    #pragma unroll
    for (int mt = 0; mt < 2; ++mt)
      #pragma unroll
      for (int nt = 0; nt < 3; ++nt)
        #pragma unroll
        for (int r = 0; r < 4; ++r) acc[mt][nt][r] = 0.0f;

    #pragma unroll
    for (int j = 0; j < 6; ++j) {
      short8 a0 = *(const short8*)&f0[j];
      short8 a1 = *(const short8*)&f1[j];
      #pragma unroll
      for (int nt = 0; nt < 3; ++nt) {
        acc[0][nt] = __builtin_amdgcn_mfma_f32_16x16x32_bf16(a0, Bf[nt][j], acc[0][nt], 0, 0, 0);
        acc[1][nt] = __builtin_amdgcn_mfma_f32_16x16x32_bf16(a1, Bf[nt][j], acc[1][nt], 0, 0, 0);
      }
    }

    // ---- gate exchange through LDS; kh0 adds the G2 pre-activation here ----
    if (kh == 0) {
      #pragma unroll
      for (int mt = 0; mt < 2; ++mt)
        #pragma unroll
        for (int nt = 0; nt < 3; ++nt) {
          ushort4v u = gpv[mt * 3 + nt];
          #pragma unroll
          for (int r = 0; r < 4; ++r)
            g_lds[g][0][mt * 16 + l4 * 4 + r][nt * 16 + l15] = acc[mt][nt][r] + bf2f(u[r]);
        }
    } else {
      #pragma unroll
      for (int mt = 0; mt < 2; ++mt)
        #pragma unroll
        for (int nt = 0; nt < 3; ++nt)
          #pragma unroll
          for (int r = 0; r < 4; ++r)
            g_lds[g][1][mt * 16 + l4 * 4 + r][nt * 16 + l15] = acc[mt][nt][r];
    }

    // ---- G2 prefetch for t+1, issued mid-step: ~1 step of cover before the next poll drains
    if (kh == 0 && t + 1 < S_) {
      int s2 = d ? (S_ - 2 - t) : (t + 1);
      const unsigned short* Gs = G2 + ((((size_t)(d * S_ + s2) * 8 + wi) * 4 + g) * 1536);
      #pragma unroll
      for (int mt = 0; mt < 2; ++mt)
        #pragma unroll
        for (int nt = 0; nt < 3; ++nt)
          gpv[mt * 3 + nt] = *(const ushort4v*)(Gs + ((mt * 3 + nt) * 4 + l4) * 64 + l15 * 4);
    }

    // SYNCa: raw barrier (lgkm only - vmcnt untouched)
    __builtin_amdgcn_sched_barrier(0);
    asm volatile("s_waitcnt lgkmcnt(0)" ::: "memory");
    __builtin_amdgcn_s_barrier();
    __builtin_amdgcn_sched_barrier(0);

    // ---- h/c update: 4 cols per thread; h write-through, no ack ----
    if (tid < 384) {
      f32x4 iv = *(const f32x4*)&g_lds[0][0][up_b][up_j] + *(const f32x4*)&g_lds[0][1][up_b][up_j];
      f32x4 fv = *(const f32x4*)&g_lds[1][0][up_b][up_j] + *(const f32x4*)&g_lds[1][1][up_b][up_j];
      f32x4 gv = *(const f32x4*)&g_lds[2][0][up_b][up_j] + *(const f32x4*)&g_lds[2][1][up_b][up_j];
      f32x4 ov = *(const f32x4*)&g_lds[3][0][up_b][up_j] + *(const f32x4*)&g_lds[3][1][up_b][up_j];
      unsigned hw[2];
      #pragma unroll
      for (int e2 = 0; e2 < 2; ++e2) {
        unsigned lohi[2];
        #pragma unroll
        for (int k = 0; k < 2; ++k) {
          int e = e2 * 2 + k;
          float c = sigm(fv[e]) * c_reg[e] + sigm(iv[e]) * tanh_fast(gv[e]);
          float h = sigm(ov[e]) * tanh_fast(c);
          c_reg[e] = c;
          lohi[k] = (unsigned)f2bf(h);
        }
        hw[e2] = lohi[0] | (lohi[1] << 16);
      }
      void* pp = (void*)(hall + (((size_t)d * S_ + s) * B_ + up_b) * HH_ + j0 + up_j);
      store_b64_wt(pp, *(uint2v*)hw);
    }

    // SYNCb: raw barrier (orders g_lds reads vs next-step writes; vmcnt untouched)
    __builtin_amdgcn_sched_barrier(0);
    asm volatile("s_waitcnt lgkmcnt(0)" ::: "memory");
    __builtin_amdgcn_s_barrier();
    __builtin_amdgcn_sched_barrier(0);
  }
}

// ---------------- Logits: [b][s][17] = concat(hf,hb) @ W_tag^T + b_tag ---------------------
__global__ __launch_bounds__(256) void logits_k(
    const unsigned short* __restrict__ hall,
    const float* __restrict__ Wtag, const float* __restrict__ btag,
    float* __restrict__ logits)
{
  int gid = blockIdx.x * blockDim.x + threadIdx.x;
  if (gid >= B_ * S_ * NT) return;
  int n = gid % NT, bs = gid / NT;
  int b_ = bs / S_, s = bs - b_ * S_;
  const unsigned short* hf = hall + (((size_t)0 * S_ + s) * B_ + b_) * HH_;
  const unsigned short* hb = hall + (((size_t)1 * S_ + s) * B_ + b_) * HH_;
  const float* w0 = Wtag + (size_t)n * (2 * HH_);
  float acc = btag[n];
  for (int k = 0; k < HH_; k += 8) {
    short8 hv = *(const short8*)(hf + k);
    #pragma unroll
    for (int j = 0; j < 8; ++j) acc += bf2f((unsigned short)hv[j]) * w0[k + j];
  }
  for (int k = 0; k < HH_; k += 8) {
    short8 hv = *(const short8*)(hb + k);
    #pragma unroll
    for (int j = 0; j < 8; ++j) acc += bf2f((unsigned short)hv[j]) * w0[HH_ + k + j];
  }
  logits[((size_t)b_ * S_ + s) * NT + n] = acc;
}

// ---------------- Viterbi (faithful: lse alpha + argmax backpointers) ----------------------
// Logits staged in LDS up-front (f32x4 coalesced); transition column in registers.
__global__ __launch_bounds__(64) void viterbi(
    const float* __restrict__ logits,   // [32][512][17]
    const int* __restrict__ mask,       // [32][512]
    const float* __restrict__ trans,    // [17][17]
    float* __restrict__ out)            // [32] scores then [32][512] paths (as float)
{
  const int b = blockIdx.x;
  const int lane = threadIdx.x;
  __shared__ float lgs[S_ * NT];        // 34816 B
  __shared__ float tr[NT * NT];
  __shared__ float alpha[NT];
  __shared__ signed char bp[S_][NT];
  __shared__ int len_s;

  {
    const f32x4* src4 = (const f32x4*)(logits + (size_t)b * S_ * NT);
    f32x4* dst4 = (f32x4*)lgs;
    for (int i = lane; i < (S_ * NT) / 4; i += 64) dst4[i] = src4[i];
  }
  int cnt = 0;
  for (int t = lane; t < S_; t += 64) cnt += mask[(size_t)b * S_ + t];
  #pragma unroll
  for (int o = 32; o > 0; o >>= 1) cnt += __shfl_down(cnt, o);
  if (lane == 0) len_s = cnt;
  for (int i = lane; i < NT * NT; i += 64) tr[i] = trans[i];
  if (lane < NT) alpha[lane] = (lane == 15) ? 0.0f : -1000.0f;
  __syncthreads();
  const int len = len_s;

  float trc[NT];   // my incoming-transition column: trc[p] = trans[p][lane]
  if (lane < NT) {
    #pragma unroll
    for (int p = 0; p < NT; ++p) trc[p] = tr[p * NT + lane];
  }

  for (int t = 0; t < S_; ++t) {
    float na = 0.f; signed char am = 0;
    if (lane < NT) {
      float v[NT];
      float best = -3.4e38f; int arg = 0;
      #pragma unroll
      for (int p = 0; p < NT; ++p) {
        float x = alpha[p] + trc[p];
        v[p] = x;
        if (x > best) { best = x; arg = p; }   // strict > keeps first max (jnp.argmax)
      }
      float ssum = 0.f;
      #pragma unroll
      for (int p = 0; p < NT; ++p) ssum += __expf(v[p] - best);
      na = lgs[t * NT + lane] + best + __logf(ssum);
      am = (signed char)arg;
    }
    __syncthreads();
    if (lane < NT) {
      if (t < len) alpha[lane] = na;
      bp[t][lane] = am;
    }
    __syncthreads();
  }

  if (lane == 0) {
    float fin[NT];
    float best = -3.4e38f; int arg = 0;
    #pragma unroll
    for (int n = 0; n < NT; ++n) {
      fin[n] = alpha[n] + tr[n * NT + 16];
      if (fin[n] > best) { best = fin[n]; arg = n; }
    }
    float ss = 0.f;
    #pragma unroll
    for (int n = 0; n < NT; ++n) ss += __expf(fin[n] - best);
    out[b] = best + __logf(ss);

    int tag = arg;
    float* po = out + B_ + (size_t)b * S_;
    for (int t = S_ - 1; t >= 0; --t) {
      int nt;
      if (t == len - 1) nt = arg;
      else if (t < len - 1) nt = bp[t + 1][tag];
      else nt = tag;
      tag = nt;
      po[t] = (t < len) ? (float)nt : -1.0f;
    }
  }
}

extern "C" void kernel_launch(void* const* d_in, const int* in_sizes, int n_in,
                              void* d_out, int out_size, void* d_ws, size_t ws_size,
                              hipStream_t stream) {
  const float* emb   = (const float*)d_in[0];
  const int*   maskp = (const int*)d_in[1];
  const float* h0    = (const float*)d_in[2];
  const float* c0    = (const float*)d_in[3];
  const float* Wihf  = (const float*)d_in[4];
  const float* Whhf  = (const float*)d_in[5];
  const float* bfp   = (const float*)d_in[6];
  const float* Wihb  = (const float*)d_in[7];
  const float* Whhb  = (const float*)d_in[8];
  const float* bbp   = (const float*)d_in[9];
  const float* Wtag  = (const float*)d_in[10];
  const float* btag  = (const float*)d_in[11];
  const float* trans = (const float*)d_in[12];
  float* out = (float*)d_out;

  char* ws = (char*)d_ws;
  const size_t szG2   = (size_t)2 * S_ * B_ * G4 * 2;      // 100663296 (bf16 frag-order)
  const size_t szEmb  = (size_t)B_ * S_ * E_ * 2;
  const size_t szWih  = (size_t)2 * G4 * E_ * 2;
  const size_t szWhh  = (size_t)2 * G4 * HH_ * 2;
  const size_t szHin  = (size_t)2 * B_ * HH_ * 2;
  const size_t szHall = (size_t)2 * S_ * B_ * HH_ * 2;
  const size_t szLog  = (size_t)B_ * S_ * NT * 4;

  size_t off = 0;
  unsigned short* G2     = (unsigned short*)(ws + off); off += szG2;
  unsigned short* embB   = (unsigned short*)(ws + off); off += szEmb;
  unsigned short* WihB   = (unsigned short*)(ws + off); off += szWih;
  unsigned short* WhhB   = (unsigned short*)(ws + off); off += szWhh;
  unsigned short* hinitB = (unsigned short*)(ws + off); off += szHin;
  unsigned short* hallB  = (unsigned short*)(ws + off); off += szHall;
  float*          logits = (float*)(ws + off);          off += szLog;
  if (ws_size < off) return;

  // poison hall with the sentinel byte (0x7F7F7F7F dwords) - data-embedded sync
  hipMemsetAsync(hallB, 0x7F, szHall, stream);

  cvt_bf16<<<2048, 256, 0, stream>>>(emb,  embB, B_ * S_ * E_);
  cvt_bf16<<<256, 256, 0, stream>>>(Wihf, WihB, G4 * E_);
  cvt_bf16<<<256, 256, 0, stream>>>(Wihb, WihB + (size_t)G4 * E_, G4 * E_);
  cvt_bf16<<<128, 256, 0, stream>>>(Whhf, WhhB, G4 * HH_);
  cvt_bf16<<<128, 256, 0, stream>>>(Whhb, WhhB + (size_t)G4 * HH_, G4 * HH_);
  cvt_bf16<<<48, 256, 0, stream>>>(h0, hinitB, 2 * B_ * HH_);

  gemm_input<<<dim3(G4 / 128, (S_ * B_) / 128, 2), 256, 0, stream>>>(embB, WihB, bfp, bbp, G2);
  lstm_rec<<<16, 512, 0, stream>>>(WhhB, hinitB, c0, G2, hallB);
  logits_k<<<(B_ * S_ * NT + 255) / 256, 256, 0, stream>>>(hallB, Wtag, btag, logits);
  viterbi<<<B_, 64, 0, stream>>>(logits, maskp, trans, out);

  (void)in_sizes; (void)n_in; (void)out_size; (void)ws_size;
}